// Round 6
// baseline (1837.385 us; speedup 1.0000x reference)
//
#include <hip/hip_runtime.h>
#include <hip/hip_cooperative_groups.h>
#include <stdint.h>

namespace cg = cooperative_groups;

// ============================================================================
// SynthID watermark processor — round 6: alignbit threefry (1-op rotl),
// cooperative fused radix+chunks (12 launches -> 1), adaptive binsel margin,
// 4-token/thread coarsened mid passes.
// RNG: jax_threefry_partitionable=True (validated r1-r5).
// ============================================================================

#define NB 32
#define NV 128000
#define NDEPTH 16
#define NTB 500        // 256-token blocks per batch (gmask)
#define NCB 125        // 1024-token blocks per batch (coarsened passes)
#define NBINS 512      // exponent bins = key >> 23
#define CAP 96256      // head capacity per batch (94*1024)
#define NBLKH 94       // head radix chunks (1024 elems each) per batch
#define RBLOCKS 1024   // cooperative radix grid
#define FPSCALE 17592186044416.0          // 2^44 (p0 fixed point)
#define TSCALE  68719476736.0             // 2^36 (weighted mass fixed point)
#define MSCALE 1.152921504606846976e18    // 2^60 (bin mass)

typedef unsigned long long u64;

// single-instruction rotate-left: v_alignbit_b32(v, v, 32-r) == rotl(v, r)
__device__ __forceinline__ uint32_t rotl32(uint32_t v, int r) {
  return __builtin_amdgcn_alignbit(v, v, (32 - r) & 31);
}

__device__ __forceinline__ void tf2x32(uint32_t k0, uint32_t k1,
                                       uint32_t x0, uint32_t x1,
                                       uint32_t &o0, uint32_t &o1) {
  uint32_t ks2 = k0 ^ k1 ^ 0x1BD11BDAu;
  x0 += k0; x1 += k1;
  x0 += x1; x1 = rotl32(x1, 13); x1 ^= x0;
  x0 += x1; x1 = rotl32(x1, 15); x1 ^= x0;
  x0 += x1; x1 = rotl32(x1, 26); x1 ^= x0;
  x0 += x1; x1 = rotl32(x1,  6); x1 ^= x0;
  x0 += k1; x1 += ks2 + 1u;
  x0 += x1; x1 = rotl32(x1, 17); x1 ^= x0;
  x0 += x1; x1 = rotl32(x1, 29); x1 ^= x0;
  x0 += x1; x1 = rotl32(x1, 16); x1 ^= x0;
  x0 += x1; x1 = rotl32(x1, 24); x1 ^= x0;
  x0 += ks2; x1 += k0 + 2u;
  x0 += x1; x1 = rotl32(x1, 13); x1 ^= x0;
  x0 += x1; x1 = rotl32(x1, 15); x1 ^= x0;
  x0 += x1; x1 = rotl32(x1, 26); x1 ^= x0;
  x0 += x1; x1 = rotl32(x1,  6); x1 ^= x0;
  x0 += k0; x1 += k1 + 3u;
  x0 += x1; x1 = rotl32(x1, 17); x1 ^= x0;
  x0 += x1; x1 = rotl32(x1, 29); x1 ^= x0;
  x0 += x1; x1 = rotl32(x1, 16); x1 ^= x0;
  x0 += x1; x1 = rotl32(x1, 24); x1 ^= x0;
  x0 += k1; x1 += ks2 + 4u;
  x0 += x1; x1 = rotl32(x1, 13); x1 ^= x0;
  x0 += x1; x1 = rotl32(x1, 15); x1 ^= x0;
  x0 += x1; x1 = rotl32(x1, 26); x1 ^= x0;
  x0 += x1; x1 = rotl32(x1,  6); x1 ^= x0;
  x0 += ks2; x1 += k0 + 5u;
  o0 = x0; o1 = x1;
}

__device__ __forceinline__ uint32_t random_bits32(uint32_t k0, uint32_t k1, uint32_t i) {
  uint32_t y0, y1;
  tf2x32(k0, k1, 0u, i, y0, y1);
  return y0 ^ y1;
}

// ---------------------------------------------------------------------------
__global__ void keys_k(const int* __restrict__ ids, int T,
                       uint32_t* __restrict__ kd, uint32_t* __restrict__ sk) {
  int t = threadIdx.x;
  if (t >= NB) return;
  uint32_t prior = 0;
  for (int q = 0; q < 4; ++q) prior += (uint32_t)ids[(size_t)t * T + (T - 4) + q];
  uint32_t b0, b1;
  tf2x32(0u, 0u, 0u, prior, b0, b1);
  for (int d = 0; d < NDEPTH; ++d) {
    uint32_t y0, y1;
    tf2x32(b0, b1, 0u, (uint32_t)d, y0, y1);
    kd[(t * NDEPTH + d) * 2 + 0] = y0;
    kd[(t * NDEPTH + d) * 2 + 1] = y1;
  }
  uint32_t s0, s1;
  tf2x32(0u, 1u, 0u, (uint32_t)t, s0, s1);
  sk[2 * t + 0] = s0;
  sk[2 * t + 1] = s1;
}

// gmask (SGPR keys, unrolled, 2-op pack) + per-256-token block max of logits
__global__ void gmaskmax_k(const uint32_t* __restrict__ kd, const float* __restrict__ logits,
                           uint16_t* __restrict__ mask, float* __restrict__ pmax) {
  int blk = blockIdx.x, t = threadIdx.x;
  int b = blk / NTB, c = blk % NTB;
  uint32_t v = (uint32_t)(c * 256 + t);
  size_t i = (size_t)b * NV + v;
  const uint32_t* kp = kd + b * NDEPTH * 2;
  uint32_t m = 0;
  #pragma unroll
  for (int d = NDEPTH - 1; d >= 0; --d) {
    uint32_t k0 = __builtin_amdgcn_readfirstlane(kp[2 * d]);
    uint32_t k1 = __builtin_amdgcn_readfirstlane(kp[2 * d + 1]);
    uint32_t bits = random_bits32(k0, k1, v);
    m = (m << 1) | (bits >> 31);          // accumulate "false" indicator
  }
  mask[i] = (uint16_t)(m ^ 0xFFFFu);      // bernoulli true <=> top bit 0
  float x = logits[i];
  for (int o = 32; o > 0; o >>= 1) x = fmaxf(x, __shfl_xor(x, o));
  __shared__ float wmax[4];
  if ((t & 63) == 0) wmax[t >> 6] = x;
  __syncthreads();
  if (t == 0) pmax[b * NTB + c] = fmaxf(fmaxf(wmax[0], wmax[1]), fmaxf(wmax[2], wmax[3]));
}

__global__ void maxr2_k(const float* __restrict__ pmax, float* __restrict__ mx) {
  int t = threadIdx.x;
  int b = t >> 5, k = t & 31;
  float m = -3.4e38f;
  for (int i = k; i < NTB; i += 32) m = fmaxf(m, pmax[b * NTB + i]);
  for (int o = 16; o > 0; o >>= 1) m = fmaxf(m, __shfl_xor(m, o, 32));
  if (k == 0) mx[b] = m;
}

// 256-bin low-byte histogram of fixed-point p0; caches ef. 4 tokens/thread.
__global__ void lohist_k(const float* __restrict__ logits, const uint16_t* __restrict__ mask,
                         const float* __restrict__ mx, float* __restrict__ ef,
                         u64* __restrict__ Hlo) {
  int blk = blockIdx.x, t = threadIdx.x;
  int b = blk / NCB, c = blk % NCB;
  __shared__ u64 h[256];
  h[t] = 0ull;
  __syncthreads();
  float mxb = mx[b];
  size_t base = (size_t)b * NV + (size_t)c * 1024;
  #pragma unroll
  for (int e = 0; e < 4; ++e) {
    size_t i = base + e * 256 + t;
    float x = expf(logits[i] - mxb);
    ef[i] = x;
    atomicAdd(&h[mask[i] & 255u], (u64)((double)x * FPSCALE));
  }
  __syncthreads();
  if (h[t]) atomicAdd(&Hlo[b * 256 + t], h[t]);
}

// depths 0..7 on the 256-entry low histogram; exact integer Z; emits W_lo table
__global__ void faclo_k(const u64* __restrict__ Hlo, u64* __restrict__ Zint,
                        float* __restrict__ zf, float* __restrict__ gm,
                        float* __restrict__ wloTab) {
  int b = blockIdx.x, t = threadIdx.x;
  u64 v = Hlo[b * 256 + t];
  __shared__ u64 zr[256];
  zr[t] = v; __syncthreads();
  for (int s = 128; s > 0; s >>= 1) { if (t < s) zr[t] += zr[t + s]; __syncthreads(); }
  __shared__ double Zsh;
  if (t == 0) {
    Zint[b] = zr[0];
    Zsh = (double)zr[0] * (1.0 / FPSCALE);
    zf[b] = (float)Zsh;
  }
  __syncthreads();
  double Zd = Zsh;
  float base = (float)((double)v * (1.0 / FPSCALE) / Zd);
  float w = 1.0f;
  __shared__ double dr[256];
  for (int d = 0; d < 8; ++d) {
    int bit = (t >> d) & 1;
    dr[t] = bit ? (double)(base * w) : 0.0;
    __syncthreads();
    for (int s = 128; s > 0; s >>= 1) { if (t < s) dr[t] += dr[t + s]; __syncthreads(); }
    float g = (float)dr[0];
    if (t == 0) gm[b * NDEPTH + d] = g;
    w *= (1.0f + (float)bit) - g;
    __syncthreads();
  }
  wloTab[b * 256 + t] = w;
}

// 256-bin high-byte histogram of p0 * W_lo(lo). 4 tokens/thread.
__global__ void hihist_k(const float* __restrict__ ef, const uint16_t* __restrict__ mask,
                         const float* __restrict__ wloTab, u64* __restrict__ Thist) {
  int blk = blockIdx.x, t = threadIdx.x;
  int b = blk / NCB, c = blk % NCB;
  __shared__ u64 h[256];
  __shared__ float wl[256];
  h[t] = 0ull;
  wl[t] = wloTab[b * 256 + t];
  __syncthreads();
  size_t base = (size_t)b * NV + (size_t)c * 1024;
  #pragma unroll
  for (int e = 0; e < 4; ++e) {
    size_t i = base + e * 256 + t;
    uint32_t mk = mask[i];
    double prod = (double)ef[i] * (double)wl[mk & 255u];
    atomicAdd(&h[mk >> 8], (u64)(prod * TSCALE));
  }
  __syncthreads();
  if (h[t]) atomicAdd(&Thist[b * 256 + t], h[t]);
}

// depths 8..15 on the 256-entry weighted high histogram
__global__ void fachi_k(const u64* __restrict__ Thist, const u64* __restrict__ Zint,
                        float* __restrict__ gm) {
  int b = blockIdx.x, t = threadIdx.x;
  double Zd = (double)Zint[b] * (1.0 / FPSCALE);
  u64 v = Thist[b * 256 + t];
  float base = (float)((double)v * (1.0 / TSCALE) / Zd);
  float w = 1.0f;
  __shared__ double dr[256];
  for (int d = 8; d < NDEPTH; ++d) {
    int bit = (t >> (d - 8)) & 1;
    dr[t] = bit ? (double)(base * w) : 0.0;
    __syncthreads();
    for (int s = 128; s > 0; s >>= 1) { if (t < s) dr[t] += dr[t + s]; __syncthreads(); }
    float g = (float)dr[0];
    if (t == 0) gm[b * NDEPTH + d] = g;
    w *= (1.0f + (float)bit) - g;
    __syncthreads();
  }
}

// final p (exact per-token chain) -> keys in place + 512-bin histos. 4/thread.
__global__ void final_k(float* __restrict__ efkeys, const uint16_t* __restrict__ mask,
                        const float* __restrict__ zf, const float* __restrict__ gm,
                        u64* __restrict__ binmass, uint32_t* __restrict__ bincnt) {
  int blk = blockIdx.x, t = threadIdx.x;
  int b = blk / NCB, c = blk % NCB;
  __shared__ float gsh[NDEPTH];
  __shared__ float zsh;
  __shared__ u64 bm[NBINS];
  __shared__ uint32_t bc[NBINS];
  if (t < NDEPTH) gsh[t] = gm[b * NDEPTH + t];
  if (t == 16) zsh = zf[b];
  for (int i = t; i < NBINS; i += 256) { bm[i] = 0ull; bc[i] = 0u; }
  __syncthreads();
  size_t base = (size_t)b * NV + (size_t)c * 1024;
  #pragma unroll
  for (int e = 0; e < 4; ++e) {
    size_t i = base + e * 256 + t;
    float p = efkeys[i] / zsh;
    uint16_t mk = mask[i];
    #pragma unroll
    for (int d = 0; d < NDEPTH; ++d) {
      float g = (float)((mk >> d) & 1);
      p = p * ((1.0f + g) - gsh[d]);
    }
    uint32_t key = ~__float_as_uint(p);
    ((uint32_t*)efkeys)[i] = key;
    uint32_t bin = key >> 23;
    atomicAdd(&bm[bin], (u64)((double)p * MSCALE));
    atomicAdd(&bc[bin], 1u);
  }
  __syncthreads();
  for (int k = t; k < NBINS; k += 256) {
    if (bc[k]) atomicAdd(&bincnt[b * NBINS + k], bc[k]);
    if (bm[k]) atomicAdd(&binmass[b * NBINS + k], bm[k]);
  }
}

// head threshold: first bin crossing 0.9f mass; ADAPTIVE margin (0 when the
// overshoot exceeds 2^22 units ~ 3.6e-12 mass >> fixed-point/f64 divergence)
__launch_bounds__(512)
__global__ void binsel_k(const u64* __restrict__ binmass, const uint32_t* __restrict__ bincnt,
                         uint32_t* __restrict__ Kthr, uint32_t* __restrict__ Hlen) {
  int b = blockIdx.x, t = threadIdx.x;
  __shared__ u64 cm[NBINS];
  __shared__ uint32_t cc[NBINS];
  __shared__ int selB;
  cm[t] = binmass[b * NBINS + t];
  cc[t] = bincnt[b * NBINS + t];
  if (t == 0) selB = NBINS - 2;
  __syncthreads();
  for (int off = 1; off < NBINS; off <<= 1) {
    u64 a = (t >= off) ? cm[t - off] : 0ull;
    uint32_t d = (t >= off) ? cc[t - off] : 0u;
    __syncthreads();
    cm[t] += a; cc[t] += d;
    __syncthreads();
  }
  const u64 thr = (u64)((double)0.9f * MSCALE);
  if (cm[t] >= thr && (t == 0 || cm[t - 1] < thr)) atomicMin(&selB, t);
  __syncthreads();
  if (t == 0) {
    int sb = selB;
    int margin = (cm[sb] >= thr && (cm[sb] - thr) > (1ull << 22)) ? 0 : 1;
    int Bs = sb + margin;
    if (Bs > NBINS - 1) Bs = NBINS - 1;
    while (Bs > 0 && cc[Bs] > CAP) --Bs;
    u64 kt = (((u64)(Bs + 1)) << 23) - 1ull;
    Kthr[b] = (uint32_t)kt;
    Hlen[b] = cc[Bs];
  }
}

// per-256-chunk head-element counts
__global__ void hcount_k(const uint32_t* __restrict__ keys, const uint32_t* __restrict__ Kthr,
                         uint32_t* __restrict__ hcnt) {
  int blk = blockIdx.x, t = threadIdx.x;
  int b = blk / NTB, c = blk % NTB;
  size_t i = (size_t)blk * 256 + t;
  bool active = keys[i] <= Kthr[b];
  u64 am = __ballot(active);
  __shared__ uint32_t wc[4];
  if ((t & 63) == 0) wc[t >> 6] = (uint32_t)__popcll(am);
  __syncthreads();
  if (t == 0) hcnt[b * NTB + c] = wc[0] + wc[1] + wc[2] + wc[3];
}

__launch_bounds__(1024)
__global__ void hscan_k(uint32_t* __restrict__ hcnt) {
  int b = blockIdx.x, t = threadIdx.x;
  uint32_t v = (t < NTB) ? hcnt[b * NTB + t] : 0u;
  __shared__ uint32_t sc[1024];
  sc[t] = v;
  __syncthreads();
  for (int off = 1; off < 1024; off <<= 1) {
    uint32_t a = (t >= off) ? sc[t - off] : 0u;
    __syncthreads();
    sc[t] += a;
    __syncthreads();
  }
  if (t < NTB) hcnt[b * NTB + t] = sc[t] - v;
}

// deterministic index-ordered compaction into head pairs
__global__ void hcompact_k(const uint32_t* __restrict__ keys, const uint32_t* __restrict__ Kthr,
                           const uint32_t* __restrict__ hcnt, uint2* __restrict__ headA) {
  int blk = blockIdx.x, t = threadIdx.x;
  int b = blk / NTB, c = blk % NTB;
  int v = c * 256 + t;
  size_t i = (size_t)blk * 256 + t;
  uint32_t key = keys[i];
  bool active = key <= Kthr[b];
  int w = t >> 6, lane = t & 63;
  u64 am = __ballot(active);
  uint32_t rank = (uint32_t)__popcll(am & ((1ull << lane) - 1ull));
  __shared__ uint32_t wc[4];
  if ((t & 63) == 0) wc[t >> 6] = (uint32_t)__popcll(am);
  __syncthreads();
  uint32_t off = hcnt[b * NTB + c] + rank;
  for (int w2 = 0; w2 < w; ++w2) off += wc[w2];
  if (active) headA[(size_t)b * CAP + off] = make_uint2(key, (uint32_t)v);
}

// ---------------- cooperative fused radix (4 passes) + chunk sums ----------
// cnt layout: [b][c][dig] (coalesced for hist write, scan, scatter read)
__launch_bounds__(256)
__global__ void radix_coop_k(uint2* __restrict__ A, uint2* __restrict__ B,
                             const uint32_t* __restrict__ Hlen,
                             uint32_t* __restrict__ cnt, double* __restrict__ csum) {
  cg::grid_group grid = cg::this_grid();
  int t = threadIdx.x;
  int w = t >> 6, lane = t & 63;
  u64 lowmask = (1ull << lane) - 1ull;
  __shared__ uint32_t lh[256];
  __shared__ uint32_t runb[256];
  __shared__ uint32_t wvc[4][256];
  __shared__ uint32_t dtot[256];
  __shared__ double redd[256];

  for (int pass = 0; pass < 4; ++pass) {
    int shift = pass * 8;
    const uint2* src = (pass & 1) ? B : A;
    uint2* dst = (pass & 1) ? A : B;
    // ---- hist ----
    for (int task = blockIdx.x; task < NB * NBLKH; task += RBLOCKS) {
      int b = task / NBLKH, c = task % NBLKH;
      uint32_t H = Hlen[b];
      uint32_t* cc = cnt + ((size_t)b * NBLKH + c) * 256;
      if ((uint32_t)(c * 1024) >= H) { cc[t] = 0u; continue; }
      lh[t] = 0;
      __syncthreads();
      const uint2* s = src + (size_t)b * CAP + (size_t)c * 1024;
      #pragma unroll
      for (int e = 0; e < 4; ++e) {
        uint32_t idx = (uint32_t)(c * 1024 + 256 * e + t);
        if (idx < H) atomicAdd(&lh[(s[t + 256 * e].x >> shift) & 255u], 1u);
      }
      __syncthreads();
      cc[t] = lh[t];
      __syncthreads();
    }
    grid.sync();
    // ---- scan (one block per batch) ----
    if (blockIdx.x < NB) {
      int b = blockIdx.x;
      uint32_t* cb = cnt + (size_t)b * NBLKH * 256;
      uint32_t s = 0;
      for (int c = 0; c < NBLKH; ++c) s += cb[c * 256 + t];
      dtot[t] = s;
      __syncthreads();
      for (int off = 1; off < 256; off <<= 1) {
        uint32_t a = (t >= off) ? dtot[t - off] : 0u;
        __syncthreads();
        dtot[t] += a;
        __syncthreads();
      }
      uint32_t run = dtot[t] - s;   // exclusive over digits
      for (int c = 0; c < NBLKH; ++c) {
        uint32_t v = cb[c * 256 + t];
        cb[c * 256 + t] = run;
        run += v;
      }
    }
    grid.sync();
    // ---- scatter (stable: (e, wave, lane) order == memory order) ----
    for (int task = blockIdx.x; task < NB * NBLKH; task += RBLOCKS) {
      int b = task / NBLKH, c = task % NBLKH;
      uint32_t H = Hlen[b];
      if ((uint32_t)(c * 1024) >= H) continue;
      const uint2* s = src + (size_t)b * CAP + (size_t)c * 1024;
      uint2* d = dst + (size_t)b * CAP;
      runb[t] = cnt[((size_t)b * NBLKH + c) * 256 + t];
      uint2 el[4];
      #pragma unroll
      for (int e = 0; e < 4; ++e) el[e] = s[t + 256 * e];
      #pragma unroll
      for (int e = 0; e < 4; ++e) {
        wvc[0][t] = 0; wvc[1][t] = 0; wvc[2][t] = 0; wvc[3][t] = 0;
        __syncthreads();
        bool active = (uint32_t)(c * 1024 + 256 * e + t) < H;
        uint32_t dig = active ? ((el[e].x >> shift) & 255u) : 0u;
        u64 act = __ballot(active);
        u64 m = ~0ull;
        #pragma unroll
        for (int bit = 0; bit < 8; ++bit) {
          u64 bb = __ballot((dig >> bit) & 1u);
          m &= ((dig >> bit) & 1u) ? bb : ~bb;
        }
        m &= act;
        uint32_t rank = (uint32_t)__popcll(m & lowmask);
        if (active && rank == 0) wvc[w][dig] = (uint32_t)__popcll(m);
        __syncthreads();
        if (active) {
          uint32_t off = runb[dig] + rank;
          for (int w2 = 0; w2 < w; ++w2) off += wvc[w2][dig];
          d[off] = el[e];
        }
        __syncthreads();
        runb[t] += wvc[0][t] + wvc[1][t] + wvc[2][t] + wvc[3][t];
        __syncthreads();
      }
    }
    grid.sync();
  }
  // ---- chunk sums over sorted A ----
  for (int task = blockIdx.x; task < NB * NBLKH; task += RBLOCKS) {
    int b = task / NBLKH, c = task % NBLKH;
    uint32_t H = Hlen[b];
    if ((uint32_t)(c * 1024) >= H) { if (t == 0) csum[b * NBLKH + c] = 0.0; continue; }
    const uint2* p = A + (size_t)b * CAP + (size_t)c * 1024;
    double ssum = 0.0;
    for (int k = t; k < 1024; k += 256) {
      uint32_t idx = (uint32_t)(c * 1024 + k);
      if (idx < H) ssum += (double)__uint_as_float(~p[k].x);
    }
    redd[t] = ssum;
    __syncthreads();
    for (int st = 128; st > 0; st >>= 1) {
      if (t < st) redd[t] += redd[t + st];
      __syncthreads();
    }
    if (t == 0) csum[b * NBLKH + c] = redd[0];
    __syncthreads();
  }
}

// fused: parallel cutoff (f64 chunk scan + in-chunk scan) then gumbel argmax
__launch_bounds__(1024)
__global__ void cutargmax_k(const uint2* __restrict__ sp, const double* __restrict__ cs,
                            const uint32_t* __restrict__ Hlen,
                            const uint32_t* __restrict__ sk, u64* __restrict__ best) {
  int b = blockIdx.x, t = threadIdx.x;
  const double TOPP = (double)0.9f;
  uint32_t H = Hlen[b];
  __shared__ double scd[1024];
  __shared__ int chSel;
  __shared__ double baseSel;
  __shared__ uint32_t cutSh;
  if (t == 0) { chSel = -1; baseSel = 0.0; cutSh = H - 1; }
  double v = (t < NBLKH) ? cs[b * NBLKH + t] : 0.0;
  scd[t] = v;
  __syncthreads();
  for (int off = 1; off < 1024; off <<= 1) {
    double a = (t >= off) ? scd[t - off] : 0.0;
    __syncthreads();
    scd[t] += a;
    __syncthreads();
  }
  if (t < NBLKH && scd[t] >= TOPP && (t == 0 || scd[t - 1] < TOPP)) {
    chSel = t;
    baseSel = (t == 0) ? 0.0 : scd[t - 1];
  }
  __syncthreads();
  int CH = chSel;
  if (CH >= 0) {
    double base = baseSel;
    uint32_t idx = (uint32_t)(CH * 1024 + t);
    double pv = (idx < H) ? (double)__uint_as_float(~sp[(size_t)b * CAP + idx].x) : 0.0;
    __syncthreads();
    scd[t] = pv;
    __syncthreads();
    for (int off = 1; off < 1024; off <<= 1) {
      double a = (t >= off) ? scd[t - off] : 0.0;
      __syncthreads();
      scd[t] += a;
      __syncthreads();
    }
    __shared__ int kSel;
    if (t == 0) kSel = 1023;
    __syncthreads();
    if (base + scd[t] >= TOPP && (t == 0 || base + scd[t - 1] < TOPP)) kSel = t;
    __syncthreads();
    if (t == 0) cutSh = (uint32_t)(CH * 1024 + kSel);
  }
  __syncthreads();
  // ---- gumbel argmax over j <= cut ----
  uint32_t c = cutSh;
  uint32_t k0 = sk[2 * b], k1 = sk[2 * b + 1];
  u64 loc = 0ull;
  for (uint32_t j = (uint32_t)t; j <= c; j += 1024) {
    uint32_t bits = random_bits32(k0, k1, j);
    uint32_t m = bits >> 9;
    float u = (m == 0u) ? 1.17549435e-38f : (float)m * 1.1920928955078125e-7f;
    float gum = -logf(-logf(u));
    float scv = logf(__uint_as_float(~sp[(size_t)b * CAP + j].x)) + gum;
    uint32_t su = __float_as_uint(scv);
    uint32_t ord = (su & 0x80000000u) ? ~su : (su | 0x80000000u);
    u64 pk = ((u64)ord << 32) | (u64)(0xFFFFFFFFu - j);
    loc = (pk > loc) ? pk : loc;
  }
  __shared__ u64 redm[1024];
  redm[t] = loc;
  __syncthreads();
  for (int st = 512; st > 0; st >>= 1) {
    if (t < st) {
      u64 o = redm[t + st];
      if (o > redm[t]) redm[t] = o;
    }
    __syncthreads();
  }
  if (t == 0) best[b] = redm[0];
}

__global__ void fill_k(float* __restrict__ out) {
  size_t i = (size_t)blockIdx.x * 256 + threadIdx.x;
  out[i] = 1e-5f;
}

__global__ void win_k(const u64* __restrict__ best, const uint2* __restrict__ sp,
                      float* __restrict__ out) {
  int b = threadIdx.x;
  if (b >= NB) return;
  u64 pk = best[b];
  uint32_t j = 0xFFFFFFFFu - (uint32_t)(pk & 0xFFFFFFFFull);
  uint32_t tok = sp[(size_t)b * CAP + j].y;
  out[(size_t)b * NV + tok] = 100000.0f;
}

// ---------------------------------------------------------------------------
extern "C" void kernel_launch(void* const* d_in, const int* in_sizes, int n_in,
                              void* d_out, int out_size, void* d_ws, size_t ws_size,
                              hipStream_t stream) {
  const int* ids = (const int*)d_in[0];
  const float* logits = (const float*)d_in[1];
  float* out = (float*)d_out;
  int T = in_sizes[0] / NB;

  char* w = (char*)d_ws;
  uint2*    headA = (uint2*)(w + 0);                  // 24,641,536
  uint2*    headB = (uint2*)(w + 24641536);           // 24,641,536
  uint16_t* mask  = (uint16_t*)(w + 49283072);        //  8,192,000
  // aliases:
  float*    efkeys = (float*)(w + 24641536);          // ef then keys (in headB, dead before radix)
  uint32_t* keys   = (uint32_t*)(w + 24641536);
  uint32_t* cnt    = (uint32_t*)(w + 49283072);       // 3,080,192 in mask region (mask dead after final_k)
  double*   csum   = (double*)(w + 52400000);         // 24,064 in mask region
  // non-aliased smalls:
  char* S = w + 57475072;
  float*    pmax    = (float*)(S + 0);                // 64,000
  uint32_t* hcnt    = (uint32_t*)(S + 64000);         // 64,000
  float*    mx      = (float*)(S + 128000);           // 128
  float*    zf      = (float*)(S + 128128);           // 128
  float*    gm      = (float*)(S + 128256);           // 2,048
  uint32_t* kd      = (uint32_t*)(S + 130304);        // 4,096
  uint32_t* sk      = (uint32_t*)(S + 134400);        // 256
  u64*      best    = (u64*)(S + 134656);             // 256
  uint32_t* Kthr    = (uint32_t*)(S + 134912);        // 128
  uint32_t* Hlen    = (uint32_t*)(S + 135040);        // 128
  u64*      Zint    = (u64*)(S + 135168);             // 256
  float*    wloTab  = (float*)(S + 135424);           // 32,768
  char* ZR = S + 168192;
  u64*      Hlo     = (u64*)(ZR + 0);                 // 65,536
  u64*      Thist   = (u64*)(ZR + 65536);             // 65,536
  u64*      binmass = (u64*)(ZR + 131072);            // 131,072
  uint32_t* bincnt  = (uint32_t*)(ZR + 262144);       // 65,536

  const int BVBLK = NB * NTB;   // 16,000
  const int CBLK  = NB * NCB;   //  4,000

  hipMemsetAsync(ZR, 0, 327680, stream);
  keys_k<<<1, 64, 0, stream>>>(ids, T, kd, sk);
  gmaskmax_k<<<BVBLK, 256, 0, stream>>>(kd, logits, mask, pmax);
  maxr2_k<<<1, 1024, 0, stream>>>(pmax, mx);
  lohist_k<<<CBLK, 256, 0, stream>>>(logits, mask, mx, efkeys, Hlo);
  faclo_k<<<NB, 256, 0, stream>>>(Hlo, Zint, zf, gm, wloTab);
  hihist_k<<<CBLK, 256, 0, stream>>>(efkeys, mask, wloTab, Thist);
  fachi_k<<<NB, 256, 0, stream>>>(Thist, Zint, gm);
  final_k<<<CBLK, 256, 0, stream>>>(efkeys, mask, zf, gm, binmass, bincnt);
  binsel_k<<<NB, NBINS, 0, stream>>>(binmass, bincnt, Kthr, Hlen);
  hcount_k<<<BVBLK, 256, 0, stream>>>(keys, Kthr, hcnt);
  hscan_k<<<NB, 1024, 0, stream>>>(hcnt);
  hcompact_k<<<BVBLK, 256, 0, stream>>>(keys, Kthr, hcnt, headA);

  {
    void* args[] = { (void*)&headA, (void*)&headB, (void*)&Hlen, (void*)&cnt, (void*)&csum };
    hipLaunchCooperativeKernel((void*)radix_coop_k, dim3(RBLOCKS), dim3(256), args, 0, stream);
  }

  cutargmax_k<<<NB, 1024, 0, stream>>>(headA, csum, Hlen, sk, best);
  fill_k<<<BVBLK, 256, 0, stream>>>(out);
  win_k<<<1, 32, 0, stream>>>(best, headA, out);
}

// Round 7
// 438.793 us; speedup vs baseline: 4.1874x; 4.1874x over previous
//
#include <hip/hip_runtime.h>
#include <stdint.h>

// ============================================================================
// SynthID watermark processor — round 7: revert cooperative radix (r6 was a
// 3.4x regression: grid.sync across 8 XCDs ~100us each x 13 syncs). Keep r6's
// alignbit threefry, coarsened mid passes, adaptive binsel margin.
// RNG: jax_threefry_partitionable=True (validated r1-r6).
// ============================================================================

#define NB 32
#define NV 128000
#define NDEPTH 16
#define NTB 500        // 256-token blocks per batch (gmask)
#define NCB 125        // 1024-token blocks per batch (coarsened passes)
#define NBINS 512      // exponent bins = key >> 23
#define CAP 96256      // head capacity per batch (94*1024)
#define NBLKH 94       // head radix chunks (1024 elems each) per batch
#define FPSCALE 17592186044416.0          // 2^44 (p0 fixed point)
#define TSCALE  68719476736.0             // 2^36 (weighted mass fixed point)
#define MSCALE 1.152921504606846976e18    // 2^60 (bin mass)

typedef unsigned long long u64;

// single-instruction rotate-left: v_alignbit_b32(v, v, 32-r) == rotl(v, r)
__device__ __forceinline__ uint32_t rotl32(uint32_t v, int r) {
  return __builtin_amdgcn_alignbit(v, v, (32 - r) & 31);
}

__device__ __forceinline__ void tf2x32(uint32_t k0, uint32_t k1,
                                       uint32_t x0, uint32_t x1,
                                       uint32_t &o0, uint32_t &o1) {
  uint32_t ks2 = k0 ^ k1 ^ 0x1BD11BDAu;
  x0 += k0; x1 += k1;
  x0 += x1; x1 = rotl32(x1, 13); x1 ^= x0;
  x0 += x1; x1 = rotl32(x1, 15); x1 ^= x0;
  x0 += x1; x1 = rotl32(x1, 26); x1 ^= x0;
  x0 += x1; x1 = rotl32(x1,  6); x1 ^= x0;
  x0 += k1; x1 += ks2 + 1u;
  x0 += x1; x1 = rotl32(x1, 17); x1 ^= x0;
  x0 += x1; x1 = rotl32(x1, 29); x1 ^= x0;
  x0 += x1; x1 = rotl32(x1, 16); x1 ^= x0;
  x0 += x1; x1 = rotl32(x1, 24); x1 ^= x0;
  x0 += ks2; x1 += k0 + 2u;
  x0 += x1; x1 = rotl32(x1, 13); x1 ^= x0;
  x0 += x1; x1 = rotl32(x1, 15); x1 ^= x0;
  x0 += x1; x1 = rotl32(x1, 26); x1 ^= x0;
  x0 += x1; x1 = rotl32(x1,  6); x1 ^= x0;
  x0 += k0; x1 += k1 + 3u;
  x0 += x1; x1 = rotl32(x1, 17); x1 ^= x0;
  x0 += x1; x1 = rotl32(x1, 29); x1 ^= x0;
  x0 += x1; x1 = rotl32(x1, 16); x1 ^= x0;
  x0 += x1; x1 = rotl32(x1, 24); x1 ^= x0;
  x0 += k1; x1 += ks2 + 4u;
  x0 += x1; x1 = rotl32(x1, 13); x1 ^= x0;
  x0 += x1; x1 = rotl32(x1, 15); x1 ^= x0;
  x0 += x1; x1 = rotl32(x1, 26); x1 ^= x0;
  x0 += x1; x1 = rotl32(x1,  6); x1 ^= x0;
  x0 += ks2; x1 += k0 + 5u;
  o0 = x0; o1 = x1;
}

__device__ __forceinline__ uint32_t random_bits32(uint32_t k0, uint32_t k1, uint32_t i) {
  uint32_t y0, y1;
  tf2x32(k0, k1, 0u, i, y0, y1);
  return y0 ^ y1;
}

// ---------------------------------------------------------------------------
__global__ void keys_k(const int* __restrict__ ids, int T,
                       uint32_t* __restrict__ kd, uint32_t* __restrict__ sk) {
  int t = threadIdx.x;
  if (t >= NB) return;
  uint32_t prior = 0;
  for (int q = 0; q < 4; ++q) prior += (uint32_t)ids[(size_t)t * T + (T - 4) + q];
  uint32_t b0, b1;
  tf2x32(0u, 0u, 0u, prior, b0, b1);
  for (int d = 0; d < NDEPTH; ++d) {
    uint32_t y0, y1;
    tf2x32(b0, b1, 0u, (uint32_t)d, y0, y1);
    kd[(t * NDEPTH + d) * 2 + 0] = y0;
    kd[(t * NDEPTH + d) * 2 + 1] = y1;
  }
  uint32_t s0, s1;
  tf2x32(0u, 1u, 0u, (uint32_t)t, s0, s1);
  sk[2 * t + 0] = s0;
  sk[2 * t + 1] = s1;
}

// gmask (SGPR keys, unrolled, 2-op pack) + per-256-token block max of logits
__global__ void gmaskmax_k(const uint32_t* __restrict__ kd, const float* __restrict__ logits,
                           uint16_t* __restrict__ mask, float* __restrict__ pmax) {
  int blk = blockIdx.x, t = threadIdx.x;
  int b = blk / NTB, c = blk % NTB;
  uint32_t v = (uint32_t)(c * 256 + t);
  size_t i = (size_t)b * NV + v;
  const uint32_t* kp = kd + b * NDEPTH * 2;
  uint32_t m = 0;
  #pragma unroll
  for (int d = NDEPTH - 1; d >= 0; --d) {
    uint32_t k0 = __builtin_amdgcn_readfirstlane(kp[2 * d]);
    uint32_t k1 = __builtin_amdgcn_readfirstlane(kp[2 * d + 1]);
    uint32_t bits = random_bits32(k0, k1, v);
    m = (m << 1) | (bits >> 31);          // accumulate "false" indicator
  }
  mask[i] = (uint16_t)(m ^ 0xFFFFu);      // bernoulli true <=> top bit 0
  float x = logits[i];
  for (int o = 32; o > 0; o >>= 1) x = fmaxf(x, __shfl_xor(x, o));
  __shared__ float wmax[4];
  if ((t & 63) == 0) wmax[t >> 6] = x;
  __syncthreads();
  if (t == 0) pmax[b * NTB + c] = fmaxf(fmaxf(wmax[0], wmax[1]), fmaxf(wmax[2], wmax[3]));
}

__global__ void maxr2_k(const float* __restrict__ pmax, float* __restrict__ mx) {
  int t = threadIdx.x;
  int b = t >> 5, k = t & 31;
  float m = -3.4e38f;
  for (int i = k; i < NTB; i += 32) m = fmaxf(m, pmax[b * NTB + i]);
  for (int o = 16; o > 0; o >>= 1) m = fmaxf(m, __shfl_xor(m, o, 32));
  if (k == 0) mx[b] = m;
}

// 256-bin low-byte histogram of fixed-point p0; caches ef. 4 tokens/thread.
__global__ void lohist_k(const float* __restrict__ logits, const uint16_t* __restrict__ mask,
                         const float* __restrict__ mx, float* __restrict__ ef,
                         u64* __restrict__ Hlo) {
  int blk = blockIdx.x, t = threadIdx.x;
  int b = blk / NCB, c = blk % NCB;
  __shared__ u64 h[256];
  h[t] = 0ull;
  __syncthreads();
  float mxb = mx[b];
  size_t base = (size_t)b * NV + (size_t)c * 1024;
  #pragma unroll
  for (int e = 0; e < 4; ++e) {
    size_t i = base + e * 256 + t;
    float x = expf(logits[i] - mxb);
    ef[i] = x;
    atomicAdd(&h[mask[i] & 255u], (u64)((double)x * FPSCALE));
  }
  __syncthreads();
  if (h[t]) atomicAdd(&Hlo[b * 256 + t], h[t]);
}

// depths 0..7 on the 256-entry low histogram; exact integer Z; emits W_lo table
__global__ void faclo_k(const u64* __restrict__ Hlo, u64* __restrict__ Zint,
                        float* __restrict__ zf, float* __restrict__ gm,
                        float* __restrict__ wloTab) {
  int b = blockIdx.x, t = threadIdx.x;
  u64 v = Hlo[b * 256 + t];
  __shared__ u64 zr[256];
  zr[t] = v; __syncthreads();
  for (int s = 128; s > 0; s >>= 1) { if (t < s) zr[t] += zr[t + s]; __syncthreads(); }
  __shared__ double Zsh;
  if (t == 0) {
    Zint[b] = zr[0];
    Zsh = (double)zr[0] * (1.0 / FPSCALE);
    zf[b] = (float)Zsh;
  }
  __syncthreads();
  double Zd = Zsh;
  float base = (float)((double)v * (1.0 / FPSCALE) / Zd);
  float w = 1.0f;
  __shared__ double dr[256];
  for (int d = 0; d < 8; ++d) {
    int bit = (t >> d) & 1;
    dr[t] = bit ? (double)(base * w) : 0.0;
    __syncthreads();
    for (int s = 128; s > 0; s >>= 1) { if (t < s) dr[t] += dr[t + s]; __syncthreads(); }
    float g = (float)dr[0];
    if (t == 0) gm[b * NDEPTH + d] = g;
    w *= (1.0f + (float)bit) - g;
    __syncthreads();
  }
  wloTab[b * 256 + t] = w;
}

// 256-bin high-byte histogram of p0 * W_lo(lo). 4 tokens/thread.
__global__ void hihist_k(const float* __restrict__ ef, const uint16_t* __restrict__ mask,
                         const float* __restrict__ wloTab, u64* __restrict__ Thist) {
  int blk = blockIdx.x, t = threadIdx.x;
  int b = blk / NCB, c = blk % NCB;
  __shared__ u64 h[256];
  __shared__ float wl[256];
  h[t] = 0ull;
  wl[t] = wloTab[b * 256 + t];
  __syncthreads();
  size_t base = (size_t)b * NV + (size_t)c * 1024;
  #pragma unroll
  for (int e = 0; e < 4; ++e) {
    size_t i = base + e * 256 + t;
    uint32_t mk = mask[i];
    double prod = (double)ef[i] * (double)wl[mk & 255u];
    atomicAdd(&h[mk >> 8], (u64)(prod * TSCALE));
  }
  __syncthreads();
  if (h[t]) atomicAdd(&Thist[b * 256 + t], h[t]);
}

// depths 8..15 on the 256-entry weighted high histogram
__global__ void fachi_k(const u64* __restrict__ Thist, const u64* __restrict__ Zint,
                        float* __restrict__ gm) {
  int b = blockIdx.x, t = threadIdx.x;
  double Zd = (double)Zint[b] * (1.0 / FPSCALE);
  u64 v = Thist[b * 256 + t];
  float base = (float)((double)v * (1.0 / TSCALE) / Zd);
  float w = 1.0f;
  __shared__ double dr[256];
  for (int d = 8; d < NDEPTH; ++d) {
    int bit = (t >> (d - 8)) & 1;
    dr[t] = bit ? (double)(base * w) : 0.0;
    __syncthreads();
    for (int s = 128; s > 0; s >>= 1) { if (t < s) dr[t] += dr[t + s]; __syncthreads(); }
    float g = (float)dr[0];
    if (t == 0) gm[b * NDEPTH + d] = g;
    w *= (1.0f + (float)bit) - g;
    __syncthreads();
  }
}

// final p (exact per-token chain) -> keys in place + 512-bin histos. 4/thread.
__global__ void final_k(float* __restrict__ efkeys, const uint16_t* __restrict__ mask,
                        const float* __restrict__ zf, const float* __restrict__ gm,
                        u64* __restrict__ binmass, uint32_t* __restrict__ bincnt) {
  int blk = blockIdx.x, t = threadIdx.x;
  int b = blk / NCB, c = blk % NCB;
  __shared__ float gsh[NDEPTH];
  __shared__ float zsh;
  __shared__ u64 bm[NBINS];
  __shared__ uint32_t bc[NBINS];
  if (t < NDEPTH) gsh[t] = gm[b * NDEPTH + t];
  if (t == 16) zsh = zf[b];
  for (int i = t; i < NBINS; i += 256) { bm[i] = 0ull; bc[i] = 0u; }
  __syncthreads();
  size_t base = (size_t)b * NV + (size_t)c * 1024;
  #pragma unroll
  for (int e = 0; e < 4; ++e) {
    size_t i = base + e * 256 + t;
    float p = efkeys[i] / zsh;
    uint16_t mk = mask[i];
    #pragma unroll
    for (int d = 0; d < NDEPTH; ++d) {
      float g = (float)((mk >> d) & 1);
      p = p * ((1.0f + g) - gsh[d]);
    }
    uint32_t key = ~__float_as_uint(p);
    ((uint32_t*)efkeys)[i] = key;
    uint32_t bin = key >> 23;
    atomicAdd(&bm[bin], (u64)((double)p * MSCALE));
    atomicAdd(&bc[bin], 1u);
  }
  __syncthreads();
  for (int k = t; k < NBINS; k += 256) {
    if (bc[k]) atomicAdd(&bincnt[b * NBINS + k], bc[k]);
    if (bm[k]) atomicAdd(&binmass[b * NBINS + k], bm[k]);
  }
}

// head threshold: first bin crossing 0.9f mass; adaptive margin
__launch_bounds__(512)
__global__ void binsel_k(const u64* __restrict__ binmass, const uint32_t* __restrict__ bincnt,
                         uint32_t* __restrict__ Kthr, uint32_t* __restrict__ Hlen) {
  int b = blockIdx.x, t = threadIdx.x;
  __shared__ u64 cm[NBINS];
  __shared__ uint32_t cc[NBINS];
  __shared__ int selB;
  cm[t] = binmass[b * NBINS + t];
  cc[t] = bincnt[b * NBINS + t];
  if (t == 0) selB = NBINS - 2;
  __syncthreads();
  for (int off = 1; off < NBINS; off <<= 1) {
    u64 a = (t >= off) ? cm[t - off] : 0ull;
    uint32_t d = (t >= off) ? cc[t - off] : 0u;
    __syncthreads();
    cm[t] += a; cc[t] += d;
    __syncthreads();
  }
  const u64 thr = (u64)((double)0.9f * MSCALE);
  if (cm[t] >= thr && (t == 0 || cm[t - 1] < thr)) atomicMin(&selB, t);
  __syncthreads();
  if (t == 0) {
    int sb = selB;
    int margin = (cm[sb] >= thr && (cm[sb] - thr) > (1ull << 22)) ? 0 : 1;
    int Bs = sb + margin;
    if (Bs > NBINS - 1) Bs = NBINS - 1;
    while (Bs > 0 && cc[Bs] > CAP) --Bs;
    u64 kt = (((u64)(Bs + 1)) << 23) - 1ull;
    Kthr[b] = (uint32_t)kt;
    Hlen[b] = cc[Bs];
  }
}

// per-256-chunk head-element counts
__global__ void hcount_k(const uint32_t* __restrict__ keys, const uint32_t* __restrict__ Kthr,
                         uint32_t* __restrict__ hcnt) {
  int blk = blockIdx.x, t = threadIdx.x;
  int b = blk / NTB, c = blk % NTB;
  size_t i = (size_t)blk * 256 + t;
  bool active = keys[i] <= Kthr[b];
  u64 am = __ballot(active);
  __shared__ uint32_t wc[4];
  if ((t & 63) == 0) wc[t >> 6] = (uint32_t)__popcll(am);
  __syncthreads();
  if (t == 0) hcnt[b * NTB + c] = wc[0] + wc[1] + wc[2] + wc[3];
}

__launch_bounds__(1024)
__global__ void hscan_k(uint32_t* __restrict__ hcnt) {
  int b = blockIdx.x, t = threadIdx.x;
  uint32_t v = (t < NTB) ? hcnt[b * NTB + t] : 0u;
  __shared__ uint32_t sc[1024];
  sc[t] = v;
  __syncthreads();
  for (int off = 1; off < 1024; off <<= 1) {
    uint32_t a = (t >= off) ? sc[t - off] : 0u;
    __syncthreads();
    sc[t] += a;
    __syncthreads();
  }
  if (t < NTB) hcnt[b * NTB + t] = sc[t] - v;
}

// deterministic index-ordered compaction into head pairs
__global__ void hcompact_k(const uint32_t* __restrict__ keys, const uint32_t* __restrict__ Kthr,
                           const uint32_t* __restrict__ hcnt, uint2* __restrict__ headA) {
  int blk = blockIdx.x, t = threadIdx.x;
  int b = blk / NTB, c = blk % NTB;
  int v = c * 256 + t;
  size_t i = (size_t)blk * 256 + t;
  uint32_t key = keys[i];
  bool active = key <= Kthr[b];
  int w = t >> 6, lane = t & 63;
  u64 am = __ballot(active);
  uint32_t rank = (uint32_t)__popcll(am & ((1ull << lane) - 1ull));
  __shared__ uint32_t wc[4];
  if ((t & 63) == 0) wc[t >> 6] = (uint32_t)__popcll(am);
  __syncthreads();
  uint32_t off = hcnt[b * NTB + c] + rank;
  for (int w2 = 0; w2 < w; ++w2) off += wc[w2];
  if (active) headA[(size_t)b * CAP + off] = make_uint2(key, (uint32_t)v);
}

// ---------------- head radix: 4 passes x 8 bits (early-exit, discrete) -----
__global__ void rhist_k(const uint2* __restrict__ src, const uint32_t* __restrict__ Hlen,
                        uint32_t* __restrict__ cnt, int shift) {
  int blk = blockIdx.x, t = threadIdx.x;
  int b = blk / NBLKH, c = blk % NBLKH;
  uint32_t H = Hlen[b];
  if ((uint32_t)(c * 1024) >= H) { cnt[((size_t)b * 256 + t) * NBLKH + c] = 0u; return; }
  const uint2* s = src + (size_t)b * CAP + (size_t)c * 1024;
  __shared__ uint32_t lh[256];
  lh[t] = 0;
  __syncthreads();
  #pragma unroll
  for (int e = 0; e < 4; ++e) {
    uint32_t idx = (uint32_t)(c * 1024 + 256 * e + t);
    if (idx < H) atomicAdd(&lh[(s[t + 256 * e].x >> shift) & 255u], 1u);
  }
  __syncthreads();
  cnt[((size_t)b * 256 + t) * NBLKH + c] = lh[t];
}

__launch_bounds__(1024)
__global__ void rscan_k(uint32_t* __restrict__ cnt) {
  const int NE = 256 * NBLKH;   // 24064
  const int NL = 24;
  int b = blockIdx.x, t = threadIdx.x;
  uint32_t* cc = cnt + (size_t)b * NE;
  uint32_t loc[NL];
  uint32_t s = 0;
  int base = t * NL;
  #pragma unroll
  for (int j = 0; j < NL; ++j) {
    loc[j] = (base + j < NE) ? cc[base + j] : 0u;
    s += loc[j];
  }
  __shared__ uint32_t sc[1024];
  sc[t] = s;
  __syncthreads();
  for (int off = 1; off < 1024; off <<= 1) {
    uint32_t v = (t >= off) ? sc[t - off] : 0u;
    __syncthreads();
    sc[t] += v;
    __syncthreads();
  }
  uint32_t run = sc[t] - s;
  #pragma unroll
  for (int j = 0; j < NL; ++j) {
    if (base + j < NE) { uint32_t o = loc[j]; cc[base + j] = run; run += o; }
  }
}

__launch_bounds__(256)
__global__ void rscatter_k(const uint2* __restrict__ src, uint2* __restrict__ dst,
                           const uint32_t* __restrict__ Hlen,
                           const uint32_t* __restrict__ cnt, int shift) {
  int blk = blockIdx.x, t = threadIdx.x;
  int b = blk / NBLKH, c = blk % NBLKH;
  uint32_t H = Hlen[b];
  if ((uint32_t)(c * 1024) >= H) return;
  const uint2* s = src + (size_t)b * CAP + (size_t)c * 1024;
  uint2* d = dst + (size_t)b * CAP;
  int w = t >> 6, lane = t & 63;
  __shared__ uint32_t runb[256];
  __shared__ uint32_t wvc[4][256];
  runb[t] = cnt[((size_t)b * 256 + t) * NBLKH + c];
  uint2 el[4];
  #pragma unroll
  for (int e = 0; e < 4; ++e) el[e] = s[t + 256 * e];
  u64 lowmask = (1ull << lane) - 1ull;
  #pragma unroll
  for (int e = 0; e < 4; ++e) {
    uint32_t* wf = &wvc[0][0];
    wf[t] = 0; wf[t + 256] = 0; wf[t + 512] = 0; wf[t + 768] = 0;
    __syncthreads();
    bool active = (uint32_t)(c * 1024 + 256 * e + t) < H;
    uint32_t dig = active ? ((el[e].x >> shift) & 255u) : 0u;
    u64 act = __ballot(active);
    u64 m = ~0ull;
    #pragma unroll
    for (int bit = 0; bit < 8; ++bit) {
      u64 bb = __ballot((dig >> bit) & 1u);
      m &= ((dig >> bit) & 1u) ? bb : ~bb;
    }
    m &= act;
    uint32_t rank = (uint32_t)__popcll(m & lowmask);
    if (active && rank == 0) wvc[w][dig] = (uint32_t)__popcll(m);
    __syncthreads();
    if (active) {
      uint32_t off = runb[dig] + rank;
      for (int w2 = 0; w2 < w; ++w2) off += wvc[w2][dig];
      d[off] = el[e];
    }
    __syncthreads();
    runb[t] += wvc[0][t] + wvc[1][t] + wvc[2][t] + wvc[3][t];
    __syncthreads();
  }
}

// ---------------------------------------------------------------------------
__global__ void chunks_k(const uint2* __restrict__ sp, const uint32_t* __restrict__ Hlen,
                         double* __restrict__ cs) {
  int blk = blockIdx.x, t = threadIdx.x;
  int b = blk / NBLKH, c = blk % NBLKH;
  uint32_t H = Hlen[b];
  if ((uint32_t)(c * 1024) >= H) { if (t == 0) cs[b * NBLKH + c] = 0.0; return; }
  const uint2* p = sp + (size_t)b * CAP + (size_t)c * 1024;
  double s = 0.0;
  for (int k = t; k < 1024; k += 256) {
    uint32_t idx = (uint32_t)(c * 1024 + k);
    if (idx < H) s += (double)__uint_as_float(~p[k].x);
  }
  __shared__ double red[256];
  red[t] = s; __syncthreads();
  for (int st = 128; st > 0; st >>= 1) {
    if (t < st) red[t] += red[t + st];
    __syncthreads();
  }
  if (t == 0) cs[b * NBLKH + c] = red[0];
}

// fused: parallel cutoff (f64 chunk scan + in-chunk scan) then gumbel argmax
__launch_bounds__(1024)
__global__ void cutargmax_k(const uint2* __restrict__ sp, const double* __restrict__ cs,
                            const uint32_t* __restrict__ Hlen,
                            const uint32_t* __restrict__ sk, u64* __restrict__ best) {
  int b = blockIdx.x, t = threadIdx.x;
  const double TOPP = (double)0.9f;
  uint32_t H = Hlen[b];
  __shared__ double scd[1024];
  __shared__ int chSel;
  __shared__ double baseSel;
  __shared__ uint32_t cutSh;
  if (t == 0) { chSel = -1; baseSel = 0.0; cutSh = H - 1; }
  double v = (t < NBLKH) ? cs[b * NBLKH + t] : 0.0;
  scd[t] = v;
  __syncthreads();
  for (int off = 1; off < 1024; off <<= 1) {
    double a = (t >= off) ? scd[t - off] : 0.0;
    __syncthreads();
    scd[t] += a;
    __syncthreads();
  }
  if (t < NBLKH && scd[t] >= TOPP && (t == 0 || scd[t - 1] < TOPP)) {
    chSel = t;
    baseSel = (t == 0) ? 0.0 : scd[t - 1];
  }
  __syncthreads();
  int CH = chSel;
  if (CH >= 0) {
    double base = baseSel;
    uint32_t idx = (uint32_t)(CH * 1024 + t);
    double pv = (idx < H) ? (double)__uint_as_float(~sp[(size_t)b * CAP + idx].x) : 0.0;
    __syncthreads();
    scd[t] = pv;
    __syncthreads();
    for (int off = 1; off < 1024; off <<= 1) {
      double a = (t >= off) ? scd[t - off] : 0.0;
      __syncthreads();
      scd[t] += a;
      __syncthreads();
    }
    __shared__ int kSel;
    if (t == 0) kSel = 1023;
    __syncthreads();
    if (base + scd[t] >= TOPP && (t == 0 || base + scd[t - 1] < TOPP)) kSel = t;
    __syncthreads();
    if (t == 0) cutSh = (uint32_t)(CH * 1024 + kSel);
  }
  __syncthreads();
  uint32_t c = cutSh;
  uint32_t k0 = sk[2 * b], k1 = sk[2 * b + 1];
  u64 loc = 0ull;
  for (uint32_t j = (uint32_t)t; j <= c; j += 1024) {
    uint32_t bits = random_bits32(k0, k1, j);
    uint32_t m = bits >> 9;
    float u = (m == 0u) ? 1.17549435e-38f : (float)m * 1.1920928955078125e-7f;
    float gum = -logf(-logf(u));
    float scv = logf(__uint_as_float(~sp[(size_t)b * CAP + j].x)) + gum;
    uint32_t su = __float_as_uint(scv);
    uint32_t ord = (su & 0x80000000u) ? ~su : (su | 0x80000000u);
    u64 pk = ((u64)ord << 32) | (u64)(0xFFFFFFFFu - j);
    loc = (pk > loc) ? pk : loc;
  }
  __shared__ u64 redm[1024];
  redm[t] = loc;
  __syncthreads();
  for (int st = 512; st > 0; st >>= 1) {
    if (t < st) {
      u64 o = redm[t + st];
      if (o > redm[t]) redm[t] = o;
    }
    __syncthreads();
  }
  if (t == 0) best[b] = redm[0];
}

__global__ void fill_k(float* __restrict__ out) {
  size_t i = (size_t)blockIdx.x * 256 + threadIdx.x;
  out[i] = 1e-5f;
}

__global__ void win_k(const u64* __restrict__ best, const uint2* __restrict__ sp,
                      float* __restrict__ out) {
  int b = threadIdx.x;
  if (b >= NB) return;
  u64 pk = best[b];
  uint32_t j = 0xFFFFFFFFu - (uint32_t)(pk & 0xFFFFFFFFull);
  uint32_t tok = sp[(size_t)b * CAP + j].y;
  out[(size_t)b * NV + tok] = 100000.0f;
}

// ---------------------------------------------------------------------------
extern "C" void kernel_launch(void* const* d_in, const int* in_sizes, int n_in,
                              void* d_out, int out_size, void* d_ws, size_t ws_size,
                              hipStream_t stream) {
  const int* ids = (const int*)d_in[0];
  const float* logits = (const float*)d_in[1];
  float* out = (float*)d_out;
  int T = in_sizes[0] / NB;

  char* w = (char*)d_ws;
  uint2*    headA = (uint2*)(w + 0);                  // 24,641,536
  uint2*    headB = (uint2*)(w + 24641536);           // 24,641,536
  uint16_t* mask  = (uint16_t*)(w + 49283072);        //  8,192,000
  // aliases:
  float*    efkeys = (float*)(w + 24641536);          // ef then keys (in headB, dead before radix)
  uint32_t* keys   = (uint32_t*)(w + 24641536);
  uint32_t* cnt    = (uint32_t*)(w + 49283072);       // 3,080,192 in mask region (mask dead after final_k)
  double*   csum   = (double*)(w + 52400000);         // 24,064 in mask region
  // non-aliased smalls:
  char* S = w + 57475072;
  float*    pmax    = (float*)(S + 0);                // 64,000
  uint32_t* hcnt    = (uint32_t*)(S + 64000);         // 64,000
  float*    mx      = (float*)(S + 128000);           // 128
  float*    zf      = (float*)(S + 128128);           // 128
  float*    gm      = (float*)(S + 128256);           // 2,048
  uint32_t* kd      = (uint32_t*)(S + 130304);        // 4,096
  uint32_t* sk      = (uint32_t*)(S + 134400);        // 256
  u64*      best    = (u64*)(S + 134656);             // 256
  uint32_t* Kthr    = (uint32_t*)(S + 134912);        // 128
  uint32_t* Hlen    = (uint32_t*)(S + 135040);        // 128
  u64*      Zint    = (u64*)(S + 135168);             // 256
  float*    wloTab  = (float*)(S + 135424);           // 32,768
  char* ZR = S + 168192;
  u64*      Hlo     = (u64*)(ZR + 0);                 // 65,536
  u64*      Thist   = (u64*)(ZR + 65536);             // 65,536
  u64*      binmass = (u64*)(ZR + 131072);            // 131,072
  uint32_t* bincnt  = (uint32_t*)(ZR + 262144);       // 65,536

  const int BVBLK = NB * NTB;   // 16,000
  const int CBLK  = NB * NCB;   //  4,000

  hipMemsetAsync(ZR, 0, 327680, stream);
  keys_k<<<1, 64, 0, stream>>>(ids, T, kd, sk);
  gmaskmax_k<<<BVBLK, 256, 0, stream>>>(kd, logits, mask, pmax);
  maxr2_k<<<1, 1024, 0, stream>>>(pmax, mx);
  lohist_k<<<CBLK, 256, 0, stream>>>(logits, mask, mx, efkeys, Hlo);
  faclo_k<<<NB, 256, 0, stream>>>(Hlo, Zint, zf, gm, wloTab);
  hihist_k<<<CBLK, 256, 0, stream>>>(efkeys, mask, wloTab, Thist);
  fachi_k<<<NB, 256, 0, stream>>>(Thist, Zint, gm);
  final_k<<<CBLK, 256, 0, stream>>>(efkeys, mask, zf, gm, binmass, bincnt);
  binsel_k<<<NB, NBINS, 0, stream>>>(binmass, bincnt, Kthr, Hlen);
  hcount_k<<<BVBLK, 256, 0, stream>>>(keys, Kthr, hcnt);
  hscan_k<<<NB, 1024, 0, stream>>>(hcnt);
  hcompact_k<<<BVBLK, 256, 0, stream>>>(keys, Kthr, hcnt, headA);

  const uint2* srcs[4] = { headA, headB, headA, headB };
  uint2*       dsts[4] = { headB, headA, headB, headA };
  for (int pass = 0; pass < 4; ++pass) {
    int shift = pass * 8;
    rhist_k<<<NB * NBLKH, 256, 0, stream>>>(srcs[pass], Hlen, cnt, shift);
    rscan_k<<<NB, 1024, 0, stream>>>(cnt);
    rscatter_k<<<NB * NBLKH, 256, 0, stream>>>(srcs[pass], dsts[pass], Hlen, cnt, shift);
  }

  chunks_k<<<NB * NBLKH, 256, 0, stream>>>(headA, Hlen, csum);
  cutargmax_k<<<NB, 1024, 0, stream>>>(headA, csum, Hlen, sk, best);
  fill_k<<<BVBLK, 256, 0, stream>>>(out);
  win_k<<<1, 32, 0, stream>>>(best, headA, out);
}

// Round 8
// 419.696 us; speedup vs baseline: 4.3779x; 1.0455x over previous
//
#include <hip/hip_runtime.h>
#include <stdint.h>

// ============================================================================
// SynthID watermark processor — round 8: compaction folded into radix pass 1
// (predicated full-vocab scatter), wave-shfl small kernels (faclo/fachi/binsel/
// rscan/cutargmax), fused zeroing, ef cache dropped.
// RNG: jax_threefry_partitionable=True (validated r1-r7).
// ============================================================================

#define NB 32
#define NV 128000
#define NDEPTH 16
#define NTB 500        // 256-token blocks per batch (gmask)
#define NCB 125        // 1024-token chunks per batch (full-vocab passes)
#define NBINS 512      // exponent bins = key >> 23
#define CAP 96256      // head capacity per batch (94*1024)
#define NBLKH 94       // head radix chunks (1024 elems each) per batch
#define FPSCALE 17592186044416.0          // 2^44 (p0 fixed point)
#define TSCALE  68719476736.0             // 2^36 (weighted mass fixed point)
#define MSCALE 1.152921504606846976e18    // 2^60 (bin mass)

typedef unsigned long long u64;

__device__ __forceinline__ uint32_t rotl32(uint32_t v, int r) {
  return __builtin_amdgcn_alignbit(v, v, (32 - r) & 31);
}

__device__ __forceinline__ void tf2x32(uint32_t k0, uint32_t k1,
                                       uint32_t x0, uint32_t x1,
                                       uint32_t &o0, uint32_t &o1) {
  uint32_t ks2 = k0 ^ k1 ^ 0x1BD11BDAu;
  x0 += k0; x1 += k1;
  x0 += x1; x1 = rotl32(x1, 13); x1 ^= x0;
  x0 += x1; x1 = rotl32(x1, 15); x1 ^= x0;
  x0 += x1; x1 = rotl32(x1, 26); x1 ^= x0;
  x0 += x1; x1 = rotl32(x1,  6); x1 ^= x0;
  x0 += k1; x1 += ks2 + 1u;
  x0 += x1; x1 = rotl32(x1, 17); x1 ^= x0;
  x0 += x1; x1 = rotl32(x1, 29); x1 ^= x0;
  x0 += x1; x1 = rotl32(x1, 16); x1 ^= x0;
  x0 += x1; x1 = rotl32(x1, 24); x1 ^= x0;
  x0 += ks2; x1 += k0 + 2u;
  x0 += x1; x1 = rotl32(x1, 13); x1 ^= x0;
  x0 += x1; x1 = rotl32(x1, 15); x1 ^= x0;
  x0 += x1; x1 = rotl32(x1, 26); x1 ^= x0;
  x0 += x1; x1 = rotl32(x1,  6); x1 ^= x0;
  x0 += k0; x1 += k1 + 3u;
  x0 += x1; x1 = rotl32(x1, 17); x1 ^= x0;
  x0 += x1; x1 = rotl32(x1, 29); x1 ^= x0;
  x0 += x1; x1 = rotl32(x1, 16); x1 ^= x0;
  x0 += x1; x1 = rotl32(x1, 24); x1 ^= x0;
  x0 += k1; x1 += ks2 + 4u;
  x0 += x1; x1 = rotl32(x1, 13); x1 ^= x0;
  x0 += x1; x1 = rotl32(x1, 15); x1 ^= x0;
  x0 += x1; x1 = rotl32(x1, 26); x1 ^= x0;
  x0 += x1; x1 = rotl32(x1,  6); x1 ^= x0;
  x0 += ks2; x1 += k0 + 5u;
  o0 = x0; o1 = x1;
}

__device__ __forceinline__ uint32_t random_bits32(uint32_t k0, uint32_t k1, uint32_t i) {
  uint32_t y0, y1;
  tf2x32(k0, k1, 0u, i, y0, y1);
  return y0 ^ y1;
}

// ---------------------------------------------------------------------------
__global__ void keys_k(const int* __restrict__ ids, int T,
                       uint32_t* __restrict__ kd, uint32_t* __restrict__ sk) {
  int t = threadIdx.x;
  if (t >= NB) return;
  uint32_t prior = 0;
  for (int q = 0; q < 4; ++q) prior += (uint32_t)ids[(size_t)t * T + (T - 4) + q];
  uint32_t b0, b1;
  tf2x32(0u, 0u, 0u, prior, b0, b1);
  for (int d = 0; d < NDEPTH; ++d) {
    uint32_t y0, y1;
    tf2x32(b0, b1, 0u, (uint32_t)d, y0, y1);
    kd[(t * NDEPTH + d) * 2 + 0] = y0;
    kd[(t * NDEPTH + d) * 2 + 1] = y1;
  }
  uint32_t s0, s1;
  tf2x32(0u, 1u, 0u, (uint32_t)t, s0, s1);
  sk[2 * t + 0] = s0;
  sk[2 * t + 1] = s1;
}

// gmask + per-256-token block max of logits + fused histogram zeroing
__global__ void gmaskmax_k(const uint32_t* __restrict__ kd, const float* __restrict__ logits,
                           uint16_t* __restrict__ mask, float* __restrict__ pmax,
                           uint32_t* __restrict__ ZR) {
  int blk = blockIdx.x, t = threadIdx.x;
  if (blk < 320) ZR[blk * 256 + t] = 0u;   // zero 327,680 B of histogram region
  int b = blk / NTB, c = blk % NTB;
  // hoist keys once per block (uniform loads -> SGPR-resident)
  uint32_t K0[NDEPTH], K1[NDEPTH];
  #pragma unroll
  for (int d = 0; d < NDEPTH; ++d) {
    K0[d] = kd[b * NDEPTH * 2 + 2 * d];
    K1[d] = kd[b * NDEPTH * 2 + 2 * d + 1];
  }
  uint32_t v = (uint32_t)(c * 256 + t);
  size_t i = (size_t)b * NV + v;
  uint32_t m = 0;
  #pragma unroll
  for (int d = NDEPTH - 1; d >= 0; --d) {
    uint32_t bits = random_bits32(K0[d], K1[d], v);
    m = __builtin_amdgcn_alignbit(m, bits, 31);   // m = (m<<1)|(bits>>31)
  }
  mask[i] = (uint16_t)(m ^ 0xFFFFu);              // bernoulli true <=> top bit 0
  float x = logits[i];
  for (int o = 32; o > 0; o >>= 1) x = fmaxf(x, __shfl_xor(x, o));
  __shared__ float wmax[4];
  if ((t & 63) == 0) wmax[t >> 6] = x;
  __syncthreads();
  if (t == 0) pmax[b * NTB + c] = fmaxf(fmaxf(wmax[0], wmax[1]), fmaxf(wmax[2], wmax[3]));
}

__global__ void maxr2_k(const float* __restrict__ pmax, float* __restrict__ mx) {
  int t = threadIdx.x;
  int b = t >> 5, k = t & 31;
  float m = -3.4e38f;
  for (int i = k; i < NTB; i += 32) m = fmaxf(m, pmax[b * NTB + i]);
  for (int o = 16; o > 0; o >>= 1) m = fmaxf(m, __shfl_xor(m, o, 32));
  if (k == 0) mx[b] = m;
}

// 256-bin low-byte histogram of fixed-point p0. 4 tokens/thread.
__global__ void lohist_k(const float* __restrict__ logits, const uint16_t* __restrict__ mask,
                         const float* __restrict__ mx, u64* __restrict__ Hlo) {
  int blk = blockIdx.x, t = threadIdx.x;
  int b = blk / NCB, c = blk % NCB;
  __shared__ u64 h[256];
  h[t] = 0ull;
  __syncthreads();
  float mxb = mx[b];
  size_t base = (size_t)b * NV + (size_t)c * 1024;
  #pragma unroll
  for (int e = 0; e < 4; ++e) {
    size_t i = base + e * 256 + t;
    float x = expf(logits[i] - mxb);
    atomicAdd(&h[mask[i] & 255u], (u64)((double)x * FPSCALE));
  }
  __syncthreads();
  if (h[t]) atomicAdd(&Hlo[b * 256 + t], h[t]);
}

// depths 0..7: single-wave, bins in registers, zero barriers
__global__ void faclo_k(const u64* __restrict__ Hlo, u64* __restrict__ Zint,
                        float* __restrict__ zf, float* __restrict__ gm,
                        float* __restrict__ wloTab) {
  int b = blockIdx.x, l = threadIdx.x;   // block = 64
  u64 v[4];
  #pragma unroll
  for (int q = 0; q < 4; ++q) v[q] = Hlo[b * 256 + l + 64 * q];
  u64 zp = v[0] + v[1] + v[2] + v[3];
  for (int o = 32; o > 0; o >>= 1) zp += __shfl_xor(zp, o);
  double Zd = (double)zp * (1.0 / FPSCALE);
  if (l == 0) { Zint[b] = zp; zf[b] = (float)Zd; }
  float base[4], w[4];
  #pragma unroll
  for (int q = 0; q < 4; ++q) {
    base[q] = (float)((double)v[q] * (1.0 / FPSCALE) / Zd);
    w[q] = 1.0f;
  }
  #pragma unroll
  for (int d = 0; d < 8; ++d) {
    double part = 0.0;
    #pragma unroll
    for (int q = 0; q < 4; ++q)
      if (((l + 64 * q) >> d) & 1) part += (double)(base[q] * w[q]);
    for (int o = 32; o > 0; o >>= 1) part += __shfl_xor(part, o);
    float g = (float)part;
    if (l == 0) gm[b * NDEPTH + d] = g;
    #pragma unroll
    for (int q = 0; q < 4; ++q) {
      int bit = ((l + 64 * q) >> d) & 1;
      w[q] *= (1.0f + (float)bit) - g;
    }
  }
  #pragma unroll
  for (int q = 0; q < 4; ++q) wloTab[b * 256 + l + 64 * q] = w[q];
}

// 256-bin high-byte histogram of p0 * W_lo(lo). 4 tokens/thread.
__global__ void hihist_k(const float* __restrict__ logits, const uint16_t* __restrict__ mask,
                         const float* __restrict__ mx, const float* __restrict__ wloTab,
                         u64* __restrict__ Thist) {
  int blk = blockIdx.x, t = threadIdx.x;
  int b = blk / NCB, c = blk % NCB;
  __shared__ u64 h[256];
  __shared__ float wl[256];
  h[t] = 0ull;
  wl[t] = wloTab[b * 256 + t];
  __syncthreads();
  float mxb = mx[b];
  size_t base = (size_t)b * NV + (size_t)c * 1024;
  #pragma unroll
  for (int e = 0; e < 4; ++e) {
    size_t i = base + e * 256 + t;
    float x = expf(logits[i] - mxb);
    uint32_t mk = mask[i];
    double prod = (double)x * (double)wl[mk & 255u];
    atomicAdd(&h[mk >> 8], (u64)(prod * TSCALE));
  }
  __syncthreads();
  if (h[t]) atomicAdd(&Thist[b * 256 + t], h[t]);
}

// depths 8..15: single-wave
__global__ void fachi_k(const u64* __restrict__ Thist, const u64* __restrict__ Zint,
                        float* __restrict__ gm) {
  int b = blockIdx.x, l = threadIdx.x;   // block = 64
  double Zd = (double)Zint[b] * (1.0 / FPSCALE);
  u64 v[4];
  #pragma unroll
  for (int q = 0; q < 4; ++q) v[q] = Thist[b * 256 + l + 64 * q];
  float base[4], w[4];
  #pragma unroll
  for (int q = 0; q < 4; ++q) {
    base[q] = (float)((double)v[q] * (1.0 / TSCALE) / Zd);
    w[q] = 1.0f;
  }
  #pragma unroll
  for (int d = 8; d < NDEPTH; ++d) {
    double part = 0.0;
    #pragma unroll
    for (int q = 0; q < 4; ++q)
      if (((l + 64 * q) >> (d - 8)) & 1) part += (double)(base[q] * w[q]);
    for (int o = 32; o > 0; o >>= 1) part += __shfl_xor(part, o);
    float g = (float)part;
    if (l == 0) gm[b * NDEPTH + d] = g;
    #pragma unroll
    for (int q = 0; q < 4; ++q) {
      int bit = ((l + 64 * q) >> (d - 8)) & 1;
      w[q] *= (1.0f + (float)bit) - g;
    }
  }
}

// final p (exact per-token chain) -> keys + 512-bin mass/count histos. 4/thread.
__global__ void final_k(const float* __restrict__ logits, const uint16_t* __restrict__ mask,
                        const float* __restrict__ mx, const float* __restrict__ zf,
                        const float* __restrict__ gm, uint32_t* __restrict__ keys,
                        u64* __restrict__ binmass, uint32_t* __restrict__ bincnt) {
  int blk = blockIdx.x, t = threadIdx.x;
  int b = blk / NCB, c = blk % NCB;
  __shared__ float gsh[NDEPTH];
  __shared__ float zsh, msh;
  __shared__ u64 bm[NBINS];
  __shared__ uint32_t bc[NBINS];
  if (t < NDEPTH) gsh[t] = gm[b * NDEPTH + t];
  if (t == 16) zsh = zf[b];
  if (t == 17) msh = mx[b];
  for (int i = t; i < NBINS; i += 256) { bm[i] = 0ull; bc[i] = 0u; }
  __syncthreads();
  size_t base = (size_t)b * NV + (size_t)c * 1024;
  #pragma unroll
  for (int e = 0; e < 4; ++e) {
    size_t i = base + e * 256 + t;
    float p = expf(logits[i] - msh) / zsh;
    uint16_t mk = mask[i];
    #pragma unroll
    for (int d = 0; d < NDEPTH; ++d) {
      float g = (float)((mk >> d) & 1);
      p = p * ((1.0f + g) - gsh[d]);
    }
    uint32_t key = ~__float_as_uint(p);
    keys[i] = key;
    uint32_t bin = key >> 23;
    atomicAdd(&bm[bin], (u64)((double)p * MSCALE));
    atomicAdd(&bc[bin], 1u);
  }
  __syncthreads();
  for (int k = t; k < NBINS; k += 256) {
    if (bc[k]) atomicAdd(&bincnt[b * NBINS + k], bc[k]);
    if (bm[k]) atomicAdd(&binmass[b * NBINS + k], bm[k]);
  }
}

// head threshold: single-wave register scan of 512 bins, adaptive margin
__global__ void binsel_k(const u64* __restrict__ binmass, const uint32_t* __restrict__ bincnt,
                         uint32_t* __restrict__ Kthr, uint32_t* __restrict__ Hlen) {
  int b = blockIdx.x, l = threadIdx.x;   // block = 64; lane owns bins [8l, 8l+8)
  u64 m[8]; uint32_t c[8];
  #pragma unroll
  for (int r = 0; r < 8; ++r) {
    m[r] = binmass[b * NBINS + l * 8 + r];
    c[r] = bincnt[b * NBINS + l * 8 + r];
  }
  #pragma unroll
  for (int r = 1; r < 8; ++r) { m[r] += m[r - 1]; c[r] += c[r - 1]; }
  u64 lm = m[7]; uint32_t lc = c[7];
  u64 im = lm; uint32_t ic = lc;
  for (int o = 1; o < 64; o <<= 1) {
    u64 nm = __shfl_up(im, o);
    uint32_t nc = __shfl_up(ic, o);
    if (l >= o) { im += nm; ic += nc; }
  }
  u64 baseM = im - lm;
  uint32_t baseC = ic - lc;
  __shared__ uint32_t ccL[NBINS];
  #pragma unroll
  for (int r = 0; r < 8; ++r) ccL[l * 8 + r] = baseC + c[r];
  const u64 thr = (u64)((double)0.9f * MSCALE);
  int localFirst = 8; u64 cmAt = 0ull;
  #pragma unroll
  for (int r = 0; r < 8; ++r) {
    if (localFirst == 8 && baseM + m[r] >= thr) { localFirst = r; cmAt = baseM + m[r]; }
  }
  u64 bal = __ballot(localFirst < 8);
  int selB = NBINS - 2; u64 cmSel = 0ull;
  if (bal) {
    int fl = __ffsll((unsigned long long)bal) - 1;
    int sl = __shfl(localFirst, fl);
    cmSel = __shfl(cmAt, fl);
    selB = fl * 8 + sl;
  }
  __syncthreads();
  if (l == 0) {
    int margin = (cmSel >= thr && (cmSel - thr) > (1ull << 22)) ? 0 : 1;
    int Bs = selB + margin;
    if (Bs > NBINS - 1) Bs = NBINS - 1;
    while (Bs > 0 && ccL[Bs] > CAP) --Bs;
    Kthr[b] = (uint32_t)((((u64)(Bs + 1)) << 23) - 1ull);
    Hlen[b] = ccL[Bs];
  }
}

// ---- wave-shfl scan over NE=256*NCH counters (dig-major, chunk-minor) -----
template<int NCH, int NL>
__launch_bounds__(1024)
__global__ void rscan_t(uint32_t* __restrict__ cnt) {
  const int NE = 256 * NCH;
  int b = blockIdx.x, t = threadIdx.x, l = t & 63, wv = t >> 6;
  uint32_t* cc = cnt + (size_t)b * NE;
  uint32_t loc[NL];
  uint32_t s = 0;
  int base = t * NL;
  #pragma unroll
  for (int j = 0; j < NL; ++j) {
    loc[j] = (base + j < NE) ? cc[base + j] : 0u;
    s += loc[j];
  }
  uint32_t incl = s;
  for (int o = 1; o < 64; o <<= 1) {
    uint32_t n = __shfl_up(incl, o);
    if (l >= o) incl += n;
  }
  __shared__ uint32_t wtot[16], wbase[16];
  if (l == 63) wtot[wv] = incl;
  __syncthreads();
  if (t < 16) {
    uint32_t v = wtot[t], i2 = v;
    for (int o = 1; o < 16; o <<= 1) {
      uint32_t n = __shfl_up(i2, o);
      if (t >= o) i2 += n;
    }
    wbase[t] = i2 - v;
  }
  __syncthreads();
  uint32_t run = wbase[wv] + (incl - s);
  #pragma unroll
  for (int j = 0; j < NL; ++j) {
    if (base + j < NE) { uint32_t o = loc[j]; cc[base + j] = run; run += o; }
  }
}

// ---- radix pass 1: predicated on full vocab (compaction fused) ------------
__global__ void rhist1_k(const uint32_t* __restrict__ keys, const uint32_t* __restrict__ Kthr,
                         uint32_t* __restrict__ cnt) {
  int blk = blockIdx.x, t = threadIdx.x;
  int b = blk / NCB, c = blk % NCB;
  uint32_t KT = Kthr[b];
  __shared__ uint32_t lh[256];
  lh[t] = 0;
  __syncthreads();
  size_t base = (size_t)b * NV + (size_t)c * 1024;
  #pragma unroll
  for (int e = 0; e < 4; ++e) {
    uint32_t k = keys[base + 256 * e + t];
    if (k <= KT) atomicAdd(&lh[k & 255u], 1u);
  }
  __syncthreads();
  cnt[((size_t)b * 256 + t) * NCB + c] = lh[t];
}

__launch_bounds__(256)
__global__ void rscatter1_k(const uint32_t* __restrict__ keys, const uint32_t* __restrict__ Kthr,
                            const uint32_t* __restrict__ cnt, uint2* __restrict__ dst0) {
  int blk = blockIdx.x, t = threadIdx.x;
  int b = blk / NCB, c = blk % NCB;
  uint32_t KT = Kthr[b];
  uint2* d = dst0 + (size_t)b * CAP;
  int w = t >> 6, lane = t & 63;
  __shared__ uint32_t runb[256];
  __shared__ uint32_t wvc[4][256];
  runb[t] = cnt[((size_t)b * 256 + t) * NCB + c];
  size_t base = (size_t)b * NV + (size_t)c * 1024;
  uint32_t el[4];
  #pragma unroll
  for (int e = 0; e < 4; ++e) el[e] = keys[base + 256 * e + t];
  u64 lowmask = (1ull << lane) - 1ull;
  #pragma unroll
  for (int e = 0; e < 4; ++e) {
    wvc[0][t] = 0; wvc[1][t] = 0; wvc[2][t] = 0; wvc[3][t] = 0;
    __syncthreads();
    bool active = el[e] <= KT;
    uint32_t dig = active ? (el[e] & 255u) : 0u;
    u64 act = __ballot(active);
    u64 m = ~0ull;
    #pragma unroll
    for (int bit = 0; bit < 8; ++bit) {
      u64 bb = __ballot((dig >> bit) & 1u);
      m &= ((dig >> bit) & 1u) ? bb : ~bb;
    }
    m &= act;
    uint32_t rank = (uint32_t)__popcll(m & lowmask);
    if (active && rank == 0) wvc[w][dig] = (uint32_t)__popcll(m);
    __syncthreads();
    if (active) {
      uint32_t off = runb[dig] + rank;
      for (int w2 = 0; w2 < w; ++w2) off += wvc[w2][dig];
      d[off] = make_uint2(el[e], (uint32_t)(c * 1024 + 256 * e + t));
    }
    __syncthreads();
    runb[t] += wvc[0][t] + wvc[1][t] + wvc[2][t] + wvc[3][t];
    __syncthreads();
  }
}

// ---- radix passes 2-4 on the head (early-exit) ----------------------------
__global__ void rhist_k(const uint2* __restrict__ src, const uint32_t* __restrict__ Hlen,
                        uint32_t* __restrict__ cnt, int shift) {
  int blk = blockIdx.x, t = threadIdx.x;
  int b = blk / NBLKH, c = blk % NBLKH;
  uint32_t H = Hlen[b];
  if ((uint32_t)(c * 1024) >= H) { cnt[((size_t)b * 256 + t) * NBLKH + c] = 0u; return; }
  const uint2* s = src + (size_t)b * CAP + (size_t)c * 1024;
  __shared__ uint32_t lh[256];
  lh[t] = 0;
  __syncthreads();
  #pragma unroll
  for (int e = 0; e < 4; ++e) {
    uint32_t idx = (uint32_t)(c * 1024 + 256 * e + t);
    if (idx < H) atomicAdd(&lh[(s[t + 256 * e].x >> shift) & 255u], 1u);
  }
  __syncthreads();
  cnt[((size_t)b * 256 + t) * NBLKH + c] = lh[t];
}

__launch_bounds__(256)
__global__ void rscatter_k(const uint2* __restrict__ src, uint2* __restrict__ dst,
                           const uint32_t* __restrict__ Hlen,
                           const uint32_t* __restrict__ cnt, int shift) {
  int blk = blockIdx.x, t = threadIdx.x;
  int b = blk / NBLKH, c = blk % NBLKH;
  uint32_t H = Hlen[b];
  if ((uint32_t)(c * 1024) >= H) return;
  const uint2* s = src + (size_t)b * CAP + (size_t)c * 1024;
  uint2* d = dst + (size_t)b * CAP;
  int w = t >> 6, lane = t & 63;
  __shared__ uint32_t runb[256];
  __shared__ uint32_t wvc[4][256];
  runb[t] = cnt[((size_t)b * 256 + t) * NBLKH + c];
  uint2 el[4];
  #pragma unroll
  for (int e = 0; e < 4; ++e) el[e] = s[t + 256 * e];
  u64 lowmask = (1ull << lane) - 1ull;
  #pragma unroll
  for (int e = 0; e < 4; ++e) {
    wvc[0][t] = 0; wvc[1][t] = 0; wvc[2][t] = 0; wvc[3][t] = 0;
    __syncthreads();
    bool active = (uint32_t)(c * 1024 + 256 * e + t) < H;
    uint32_t dig = active ? ((el[e].x >> shift) & 255u) : 0u;
    u64 act = __ballot(active);
    u64 m = ~0ull;
    #pragma unroll
    for (int bit = 0; bit < 8; ++bit) {
      u64 bb = __ballot((dig >> bit) & 1u);
      m &= ((dig >> bit) & 1u) ? bb : ~bb;
    }
    m &= act;
    uint32_t rank = (uint32_t)__popcll(m & lowmask);
    if (active && rank == 0) wvc[w][dig] = (uint32_t)__popcll(m);
    __syncthreads();
    if (active) {
      uint32_t off = runb[dig] + rank;
      for (int w2 = 0; w2 < w; ++w2) off += wvc[w2][dig];
      d[off] = el[e];
    }
    __syncthreads();
    runb[t] += wvc[0][t] + wvc[1][t] + wvc[2][t] + wvc[3][t];
    __syncthreads();
  }
}

// ---------------------------------------------------------------------------
__global__ void chunks_k(const uint2* __restrict__ sp, const uint32_t* __restrict__ Hlen,
                         double* __restrict__ cs) {
  int blk = blockIdx.x, t = threadIdx.x;
  int b = blk / NBLKH, c = blk % NBLKH;
  uint32_t H = Hlen[b];
  if ((uint32_t)(c * 1024) >= H) { if (t == 0) cs[b * NBLKH + c] = 0.0; return; }
  const uint2* p = sp + (size_t)b * CAP + (size_t)c * 1024;
  double s = 0.0;
  for (int k = t; k < 1024; k += 256) {
    uint32_t idx = (uint32_t)(c * 1024 + k);
    if (idx < H) s += (double)__uint_as_float(~p[k].x);
  }
  __shared__ double red[256];
  red[t] = s; __syncthreads();
  for (int st = 128; st > 0; st >>= 1) {
    if (t < st) red[t] += red[t + st];
    __syncthreads();
  }
  if (t == 0) cs[b * NBLKH + c] = red[0];
}

// fused cutoff (wave-shfl f64 scans) + gumbel argmax
__launch_bounds__(1024)
__global__ void cutargmax_k(const uint2* __restrict__ sp, const double* __restrict__ cs,
                            const uint32_t* __restrict__ Hlen,
                            const uint32_t* __restrict__ sk, u64* __restrict__ best) {
  int b = blockIdx.x, t = threadIdx.x, l = t & 63, wv = t >> 6;
  const double TOPP = (double)0.9f;
  uint32_t H = Hlen[b];
  __shared__ double sh_base;
  __shared__ int sh_ch;
  __shared__ uint32_t sh_cut;
  __shared__ double wsum[16];
  __shared__ u64 wmx[16];
  __shared__ int kSel;
  if (t == 0) { sh_ch = -1; sh_base = 0.0; sh_cut = H - 1; kSel = 1023; }
  __syncthreads();
  if (wv == 0) {
    double v0 = (l < NBLKH) ? cs[b * NBLKH + l] : 0.0;
    double v1 = (l + 64 < NBLKH) ? cs[b * NBLKH + l + 64] : 0.0;
    double i0 = v0;
    for (int o = 1; o < 64; o <<= 1) { double n = __shfl_up(i0, o); if (l >= o) i0 += n; }
    double T0 = __shfl(i0, 63);
    double i1 = v1;
    for (int o = 1; o < 64; o <<= 1) { double n = __shfl_up(i1, o); if (l >= o) i1 += n; }
    i1 += T0;
    bool h0 = (l < NBLKH) && (i0 >= TOPP);
    bool h1 = (l + 64 < NBLKH) && (i1 >= TOPP);
    u64 b0m = __ballot(h0);
    u64 b1m = __ballot(h1);
    int ch = -1; double bse = 0.0;
    if (b0m) {
      int fl = __ffsll((unsigned long long)b0m) - 1;
      ch = fl; bse = __shfl(i0, fl) - __shfl(v0, fl);
    } else if (b1m) {
      int fl = __ffsll((unsigned long long)b1m) - 1;
      ch = 64 + fl; bse = __shfl(i1, fl) - __shfl(v1, fl);
    }
    if (l == 0) { sh_ch = ch; sh_base = bse; }
  }
  __syncthreads();
  int CH = sh_ch;
  if (CH >= 0) {
    double base = sh_base;
    uint32_t idx = (uint32_t)(CH * 1024 + t);
    double pv = (idx < H) ? (double)__uint_as_float(~sp[(size_t)b * CAP + idx].x) : 0.0;
    double iv = pv;
    for (int o = 1; o < 64; o <<= 1) { double n = __shfl_up(iv, o); if (l >= o) iv += n; }
    if (l == 63) wsum[wv] = iv;
    __syncthreads();
    if (t < 16) {
      double v = wsum[t], i2 = v;
      for (int o = 1; o < 16; o <<= 1) { double n = __shfl_up(i2, o); if (t >= o) i2 += n; }
      wsum[t] = i2 - v;
    }
    __syncthreads();
    double full = base + wsum[wv] + iv;
    double prev = full - pv;
    if (full >= TOPP && prev < TOPP) atomicMin(&kSel, (int)t);
    __syncthreads();
    if (t == 0) sh_cut = (uint32_t)(CH * 1024 + (kSel < 1024 ? kSel : 1023));
  }
  __syncthreads();
  uint32_t c = sh_cut;
  uint32_t k0 = sk[2 * b], k1 = sk[2 * b + 1];
  u64 loc = 0ull;
  for (uint32_t j = (uint32_t)t; j <= c; j += 1024) {
    uint32_t bits = random_bits32(k0, k1, j);
    uint32_t m = bits >> 9;
    float u = (m == 0u) ? 1.17549435e-38f : (float)m * 1.1920928955078125e-7f;
    float gum = -logf(-logf(u));
    float scv = logf(__uint_as_float(~sp[(size_t)b * CAP + j].x)) + gum;
    uint32_t su = __float_as_uint(scv);
    uint32_t ord = (su & 0x80000000u) ? ~su : (su | 0x80000000u);
    u64 pk = ((u64)ord << 32) | (u64)(0xFFFFFFFFu - j);
    loc = (pk > loc) ? pk : loc;
  }
  for (int o = 32; o > 0; o >>= 1) {
    u64 oth = __shfl_xor(loc, o);
    loc = (oth > loc) ? oth : loc;
  }
  if (l == 0) wmx[wv] = loc;
  __syncthreads();
  if (t == 0) {
    u64 m = wmx[0];
    for (int k = 1; k < 16; ++k) m = (wmx[k] > m) ? wmx[k] : m;
    best[b] = m;
  }
}

__global__ void fill_k(float* __restrict__ out) {
  size_t i = (size_t)blockIdx.x * 256 + threadIdx.x;
  out[i] = 1e-5f;
}

__global__ void win_k(const u64* __restrict__ best, const uint2* __restrict__ sp,
                      float* __restrict__ out) {
  int b = threadIdx.x;
  if (b >= NB) return;
  u64 pk = best[b];
  uint32_t j = 0xFFFFFFFFu - (uint32_t)(pk & 0xFFFFFFFFull);
  uint32_t tok = sp[(size_t)b * CAP + j].y;
  out[(size_t)b * NV + tok] = 100000.0f;
}

// ---------------------------------------------------------------------------
extern "C" void kernel_launch(void* const* d_in, const int* in_sizes, int n_in,
                              void* d_out, int out_size, void* d_ws, size_t ws_size,
                              hipStream_t stream) {
  const int* ids = (const int*)d_in[0];
  const float* logits = (const float*)d_in[1];
  float* out = (float*)d_out;
  int T = in_sizes[0] / NB;

  char* w = (char*)d_ws;
  uint2*    headA = (uint2*)(w + 0);                  // 24,641,536
  uint2*    headB = (uint2*)(w + 24641536);           // 24,641,536
  uint32_t* keys  = (uint32_t*)(w + 24641536);        // aliases headB (dead before pass 2)
  uint32_t* cnt   = (uint32_t*)(w + 49283072);        //  4,096,000
  uint16_t* mask  = (uint16_t*)(w + 53379072);        //  8,192,000
  char* S = w + 61571072;
  float*    pmax    = (float*)(S + 0);                // 64,000
  double*   csum    = (double*)(S + 64000);           // 24,064
  float*    mx      = (float*)(S + 88064);            // 128
  float*    zf      = (float*)(S + 88192);            // 128
  float*    gm      = (float*)(S + 88320);            // 2,048
  uint32_t* Kthr    = (uint32_t*)(S + 90368);         // 128
  uint32_t* Hlen    = (uint32_t*)(S + 90496);         // 128
  u64*      Zint    = (u64*)(S + 90624);              // 256
  float*    wloTab  = (float*)(S + 90880);            // 32,768
  u64*      best    = (u64*)(S + 123648);             // 256
  uint32_t* kd      = (uint32_t*)(S + 123904);        // 4,096
  uint32_t* sk      = (uint32_t*)(S + 128000);        // 256
  char* ZR = S + 128256;                              // zeroed by gmaskmax
  u64*      Hlo     = (u64*)(ZR + 0);                 // 65,536
  u64*      Thist   = (u64*)(ZR + 65536);             // 65,536
  u64*      binmass = (u64*)(ZR + 131072);            // 131,072
  uint32_t* bincnt  = (uint32_t*)(ZR + 262144);       // 65,536
  // total: 61,571,072 + 128,256 + 327,680 = 62,027,008 bytes

  const int BVBLK = NB * NTB;   // 16,000
  const int CBLK  = NB * NCB;   //  4,000

  keys_k<<<1, 64, 0, stream>>>(ids, T, kd, sk);
  gmaskmax_k<<<BVBLK, 256, 0, stream>>>(kd, logits, mask, pmax, (uint32_t*)ZR);
  maxr2_k<<<1, 1024, 0, stream>>>(pmax, mx);
  lohist_k<<<CBLK, 256, 0, stream>>>(logits, mask, mx, Hlo);
  faclo_k<<<NB, 64, 0, stream>>>(Hlo, Zint, zf, gm, wloTab);
  hihist_k<<<CBLK, 256, 0, stream>>>(logits, mask, mx, wloTab, Thist);
  fachi_k<<<NB, 64, 0, stream>>>(Thist, Zint, gm);
  final_k<<<CBLK, 256, 0, stream>>>(logits, mask, mx, zf, gm, keys, binmass, bincnt);
  binsel_k<<<NB, 64, 0, stream>>>(binmass, bincnt, Kthr, Hlen);

  // pass 1: predicated full-vocab -> compacted + LSB-sorted head in headA
  rhist1_k<<<CBLK, 256, 0, stream>>>(keys, Kthr, cnt);
  rscan_t<NCB, 32><<<NB, 1024, 0, stream>>>(cnt);
  rscatter1_k<<<CBLK, 256, 0, stream>>>(keys, Kthr, cnt, headA);

  // passes 2-4 on the head: A->B->A->B (sorted result in headB)
  const uint2* srcs[3] = { headA, headB, headA };
  uint2*       dsts[3] = { headB, headA, headB };
  for (int pass = 0; pass < 3; ++pass) {
    int shift = (pass + 1) * 8;
    rhist_k<<<NB * NBLKH, 256, 0, stream>>>(srcs[pass], Hlen, cnt, shift);
    rscan_t<NBLKH, 24><<<NB, 1024, 0, stream>>>(cnt);
    rscatter_k<<<NB * NBLKH, 256, 0, stream>>>(srcs[pass], dsts[pass], Hlen, cnt, shift);
  }

  chunks_k<<<NB * NBLKH, 256, 0, stream>>>(headB, Hlen, csum);
  cutargmax_k<<<NB, 1024, 0, stream>>>(headB, csum, Hlen, sk, best);
  fill_k<<<BVBLK, 256, 0, stream>>>(out);
  win_k<<<1, 32, 0, stream>>>(best, headB, out);
}

// Round 9
// 418.394 us; speedup vs baseline: 4.3915x; 1.0031x over previous
//
#include <hip/hip_runtime.h>
#include <stdint.h>

// ============================================================================
// SynthID watermark processor — round 9: inline-asm threefry in gmask (exactly
// 71 VALU ops/draw: v_add_u32 / v_alignbit_b32 / v_xor_b32 chain, SALU key
// schedule), fill folded into final_k. Rest identical to r8 (419.7 us).
// RNG: jax_threefry_partitionable=True (validated r1-r8).
// ============================================================================

#define NB 32
#define NV 128000
#define NDEPTH 16
#define NTB 500        // 256-token blocks per batch (gmask)
#define NCB 125        // 1024-token chunks per batch (full-vocab passes)
#define NBINS 512      // exponent bins = key >> 23
#define CAP 96256      // head capacity per batch (94*1024)
#define NBLKH 94       // head radix chunks (1024 elems each) per batch
#define FPSCALE 17592186044416.0          // 2^44 (p0 fixed point)
#define TSCALE  68719476736.0             // 2^36 (weighted mass fixed point)
#define MSCALE 1.152921504606846976e18    // 2^60 (bin mass)

typedef unsigned long long u64;

__device__ __forceinline__ uint32_t rotl32(uint32_t v, int r) {
  return __builtin_amdgcn_alignbit(v, v, (32 - r) & 31);
}

// C version (keys_k / cutargmax — cold paths)
__device__ __forceinline__ void tf2x32(uint32_t k0, uint32_t k1,
                                       uint32_t x0, uint32_t x1,
                                       uint32_t &o0, uint32_t &o1) {
  uint32_t ks2 = k0 ^ k1 ^ 0x1BD11BDAu;
  x0 += k0; x1 += k1;
  x0 += x1; x1 = rotl32(x1, 13); x1 ^= x0;
  x0 += x1; x1 = rotl32(x1, 15); x1 ^= x0;
  x0 += x1; x1 = rotl32(x1, 26); x1 ^= x0;
  x0 += x1; x1 = rotl32(x1,  6); x1 ^= x0;
  x0 += k1; x1 += ks2 + 1u;
  x0 += x1; x1 = rotl32(x1, 17); x1 ^= x0;
  x0 += x1; x1 = rotl32(x1, 29); x1 ^= x0;
  x0 += x1; x1 = rotl32(x1, 16); x1 ^= x0;
  x0 += x1; x1 = rotl32(x1, 24); x1 ^= x0;
  x0 += ks2; x1 += k0 + 2u;
  x0 += x1; x1 = rotl32(x1, 13); x1 ^= x0;
  x0 += x1; x1 = rotl32(x1, 15); x1 ^= x0;
  x0 += x1; x1 = rotl32(x1, 26); x1 ^= x0;
  x0 += x1; x1 = rotl32(x1,  6); x1 ^= x0;
  x0 += k0; x1 += k1 + 3u;
  x0 += x1; x1 = rotl32(x1, 17); x1 ^= x0;
  x0 += x1; x1 = rotl32(x1, 29); x1 ^= x0;
  x0 += x1; x1 = rotl32(x1, 16); x1 ^= x0;
  x0 += x1; x1 = rotl32(x1, 24); x1 ^= x0;
  x0 += k1; x1 += ks2 + 4u;
  x0 += x1; x1 = rotl32(x1, 13); x1 ^= x0;
  x0 += x1; x1 = rotl32(x1, 15); x1 ^= x0;
  x0 += x1; x1 = rotl32(x1, 26); x1 ^= x0;
  x0 += x1; x1 = rotl32(x1,  6); x1 ^= x0;
  x0 += ks2; x1 += k0 + 5u;
  o0 = x0; o1 = x1;
}

__device__ __forceinline__ uint32_t random_bits32(uint32_t k0, uint32_t k1, uint32_t i) {
  uint32_t y0, y1;
  tf2x32(k0, k1, 0u, i, y0, y1);
  return y0 ^ y1;
}

// One threefry round: x0 += x1; x1 = rotl(x1, 32-C); x1 ^= x0. (C = 32-rot)
#define TFR(C) \
  "v_add_u32 %[x0], %[x0], %[x1]\n\t" \
  "v_alignbit_b32 %[x1], %[x1], %[x1], " C "\n\t" \
  "v_xor_b32 %[x1], %[x1], %[x0]\n\t"

// Hot-path threefry: exactly 71 VALU ops, keys on SALU.
// kA=k0, kB=k1, kC=k0^k1^0x1BD11BDA; kC1=kC+1, kA2=kA+2, kB3=kB+3, kC4=kC+4, kA5=kA+5.
__device__ __forceinline__ uint32_t tf_xor_asm(uint32_t kA, uint32_t kB, uint32_t kC,
                                               uint32_t kC1, uint32_t kA2, uint32_t kB3,
                                               uint32_t kC4, uint32_t kA5, uint32_t vi) {
  uint32_t x0, x1;
  asm(
    // init + round 1 (rot 13 -> alignbit 19); x0 = kA + (kB + i)
    "v_add_u32 %[x1], %[kB], %[vi]\n\t"
    "v_add_u32 %[x0], %[kA], %[x1]\n\t"
    "v_alignbit_b32 %[x1], %[x1], %[x1], 19\n\t"
    "v_xor_b32 %[x1], %[x1], %[x0]\n\t"
    TFR("17") TFR("6") TFR("26")                 // rounds 2-4 (15,26,6)
    "v_add_u32 %[x0], %[kB], %[x0]\n\t"          // inject 1
    "v_add_u32 %[x1], %[kC1], %[x1]\n\t"
    TFR("15") TFR("3") TFR("16") TFR("8")        // rounds 5-8 (17,29,16,24)
    "v_add_u32 %[x0], %[kC], %[x0]\n\t"          // inject 2
    "v_add_u32 %[x1], %[kA2], %[x1]\n\t"
    TFR("19") TFR("17") TFR("6") TFR("26")       // rounds 9-12 (13,15,26,6)
    "v_add_u32 %[x0], %[kA], %[x0]\n\t"          // inject 3
    "v_add_u32 %[x1], %[kB3], %[x1]\n\t"
    TFR("15") TFR("3") TFR("16") TFR("8")        // rounds 13-16 (17,29,16,24)
    "v_add_u32 %[x0], %[kB], %[x0]\n\t"          // inject 4
    "v_add_u32 %[x1], %[kC4], %[x1]\n\t"
    TFR("19") TFR("17") TFR("6") TFR("26")       // rounds 17-20 (13,15,26,6)
    "v_add_u32 %[x0], %[kC], %[x0]\n\t"          // inject 5
    "v_add_u32 %[x1], %[kA5], %[x1]\n\t"
    : [x0] "=&v"(x0), [x1] "=&v"(x1)
    : [kA] "s"(kA), [kB] "s"(kB), [kC] "s"(kC), [kC1] "s"(kC1),
      [kA2] "s"(kA2), [kB3] "s"(kB3), [kC4] "s"(kC4), [kA5] "s"(kA5),
      [vi] "v"(vi));
  return x0 ^ x1;
}

// ---------------------------------------------------------------------------
__global__ void keys_k(const int* __restrict__ ids, int T,
                       uint32_t* __restrict__ kd, uint32_t* __restrict__ sk) {
  int t = threadIdx.x;
  if (t >= NB) return;
  uint32_t prior = 0;
  for (int q = 0; q < 4; ++q) prior += (uint32_t)ids[(size_t)t * T + (T - 4) + q];
  uint32_t b0, b1;
  tf2x32(0u, 0u, 0u, prior, b0, b1);
  for (int d = 0; d < NDEPTH; ++d) {
    uint32_t y0, y1;
    tf2x32(b0, b1, 0u, (uint32_t)d, y0, y1);
    kd[(t * NDEPTH + d) * 2 + 0] = y0;
    kd[(t * NDEPTH + d) * 2 + 1] = y1;
  }
  uint32_t s0, s1;
  tf2x32(0u, 1u, 0u, (uint32_t)t, s0, s1);
  sk[2 * t + 0] = s0;
  sk[2 * t + 1] = s1;
}

// gmask (asm threefry) + per-256-token block max + fused histogram zeroing
__global__ void gmaskmax_k(const uint32_t* __restrict__ kd, const float* __restrict__ logits,
                           uint16_t* __restrict__ mask, float* __restrict__ pmax,
                           uint32_t* __restrict__ ZR) {
  int blk = blockIdx.x, t = threadIdx.x;
  if (blk < 320) ZR[blk * 256 + t] = 0u;   // zero 327,680 B of histogram region
  int b = blk / NTB, c = blk % NTB;
  const uint32_t* kp = kd + b * NDEPTH * 2;
  uint32_t v = (uint32_t)(c * 256 + t);
  size_t i = (size_t)b * NV + v;
  uint32_t m = 0;
  #pragma unroll
  for (int d = NDEPTH - 1; d >= 0; --d) {
    uint32_t k0 = __builtin_amdgcn_readfirstlane(kp[2 * d]);
    uint32_t k1 = __builtin_amdgcn_readfirstlane(kp[2 * d + 1]);
    uint32_t ks = k0 ^ k1 ^ 0x1BD11BDAu;
    uint32_t bits = tf_xor_asm(k0, k1, ks, ks + 1u, k0 + 2u, k1 + 3u, ks + 4u, k0 + 5u, v);
    m = __builtin_amdgcn_alignbit(m, bits, 31);   // m = (m<<1)|(bits>>31)
  }
  mask[i] = (uint16_t)(m ^ 0xFFFFu);              // bernoulli true <=> top bit 0
  float x = logits[i];
  for (int o = 32; o > 0; o >>= 1) x = fmaxf(x, __shfl_xor(x, o));
  __shared__ float wmax[4];
  if ((t & 63) == 0) wmax[t >> 6] = x;
  __syncthreads();
  if (t == 0) pmax[b * NTB + c] = fmaxf(fmaxf(wmax[0], wmax[1]), fmaxf(wmax[2], wmax[3]));
}

__global__ void maxr2_k(const float* __restrict__ pmax, float* __restrict__ mx) {
  int t = threadIdx.x;
  int b = t >> 5, k = t & 31;
  float m = -3.4e38f;
  for (int i = k; i < NTB; i += 32) m = fmaxf(m, pmax[b * NTB + i]);
  for (int o = 16; o > 0; o >>= 1) m = fmaxf(m, __shfl_xor(m, o, 32));
  if (k == 0) mx[b] = m;
}

// 256-bin low-byte histogram of fixed-point p0. 4 tokens/thread.
__global__ void lohist_k(const float* __restrict__ logits, const uint16_t* __restrict__ mask,
                         const float* __restrict__ mx, u64* __restrict__ Hlo) {
  int blk = blockIdx.x, t = threadIdx.x;
  int b = blk / NCB, c = blk % NCB;
  __shared__ u64 h[256];
  h[t] = 0ull;
  __syncthreads();
  float mxb = mx[b];
  size_t base = (size_t)b * NV + (size_t)c * 1024;
  #pragma unroll
  for (int e = 0; e < 4; ++e) {
    size_t i = base + e * 256 + t;
    float x = expf(logits[i] - mxb);
    atomicAdd(&h[mask[i] & 255u], (u64)((double)x * FPSCALE));
  }
  __syncthreads();
  if (h[t]) atomicAdd(&Hlo[b * 256 + t], h[t]);
}

// depths 0..7: single-wave, bins in registers, zero barriers
__global__ void faclo_k(const u64* __restrict__ Hlo, u64* __restrict__ Zint,
                        float* __restrict__ zf, float* __restrict__ gm,
                        float* __restrict__ wloTab) {
  int b = blockIdx.x, l = threadIdx.x;   // block = 64
  u64 v[4];
  #pragma unroll
  for (int q = 0; q < 4; ++q) v[q] = Hlo[b * 256 + l + 64 * q];
  u64 zp = v[0] + v[1] + v[2] + v[3];
  for (int o = 32; o > 0; o >>= 1) zp += __shfl_xor(zp, o);
  double Zd = (double)zp * (1.0 / FPSCALE);
  if (l == 0) { Zint[b] = zp; zf[b] = (float)Zd; }
  float base[4], w[4];
  #pragma unroll
  for (int q = 0; q < 4; ++q) {
    base[q] = (float)((double)v[q] * (1.0 / FPSCALE) / Zd);
    w[q] = 1.0f;
  }
  #pragma unroll
  for (int d = 0; d < 8; ++d) {
    double part = 0.0;
    #pragma unroll
    for (int q = 0; q < 4; ++q)
      if (((l + 64 * q) >> d) & 1) part += (double)(base[q] * w[q]);
    for (int o = 32; o > 0; o >>= 1) part += __shfl_xor(part, o);
    float g = (float)part;
    if (l == 0) gm[b * NDEPTH + d] = g;
    #pragma unroll
    for (int q = 0; q < 4; ++q) {
      int bit = ((l + 64 * q) >> d) & 1;
      w[q] *= (1.0f + (float)bit) - g;
    }
  }
  #pragma unroll
  for (int q = 0; q < 4; ++q) wloTab[b * 256 + l + 64 * q] = w[q];
}

// 256-bin high-byte histogram of p0 * W_lo(lo). 4 tokens/thread.
__global__ void hihist_k(const float* __restrict__ logits, const uint16_t* __restrict__ mask,
                         const float* __restrict__ mx, const float* __restrict__ wloTab,
                         u64* __restrict__ Thist) {
  int blk = blockIdx.x, t = threadIdx.x;
  int b = blk / NCB, c = blk % NCB;
  __shared__ u64 h[256];
  __shared__ float wl[256];
  h[t] = 0ull;
  wl[t] = wloTab[b * 256 + t];
  __syncthreads();
  float mxb = mx[b];
  size_t base = (size_t)b * NV + (size_t)c * 1024;
  #pragma unroll
  for (int e = 0; e < 4; ++e) {
    size_t i = base + e * 256 + t;
    float x = expf(logits[i] - mxb);
    uint32_t mk = mask[i];
    double prod = (double)x * (double)wl[mk & 255u];
    atomicAdd(&h[mk >> 8], (u64)(prod * TSCALE));
  }
  __syncthreads();
  if (h[t]) atomicAdd(&Thist[b * 256 + t], h[t]);
}

// depths 8..15: single-wave
__global__ void fachi_k(const u64* __restrict__ Thist, const u64* __restrict__ Zint,
                        float* __restrict__ gm) {
  int b = blockIdx.x, l = threadIdx.x;   // block = 64
  double Zd = (double)Zint[b] * (1.0 / FPSCALE);
  u64 v[4];
  #pragma unroll
  for (int q = 0; q < 4; ++q) v[q] = Thist[b * 256 + l + 64 * q];
  float base[4], w[4];
  #pragma unroll
  for (int q = 0; q < 4; ++q) {
    base[q] = (float)((double)v[q] * (1.0 / TSCALE) / Zd);
    w[q] = 1.0f;
  }
  #pragma unroll
  for (int d = 8; d < NDEPTH; ++d) {
    double part = 0.0;
    #pragma unroll
    for (int q = 0; q < 4; ++q)
      if (((l + 64 * q) >> (d - 8)) & 1) part += (double)(base[q] * w[q]);
    for (int o = 32; o > 0; o >>= 1) part += __shfl_xor(part, o);
    float g = (float)part;
    if (l == 0) gm[b * NDEPTH + d] = g;
    #pragma unroll
    for (int q = 0; q < 4; ++q) {
      int bit = ((l + 64 * q) >> (d - 8)) & 1;
      w[q] *= (1.0f + (float)bit) - g;
    }
  }
}

// final p (exact per-token chain) -> keys + 512-bin histos + 1e-5 background.
__global__ void final_k(const float* __restrict__ logits, const uint16_t* __restrict__ mask,
                        const float* __restrict__ mx, const float* __restrict__ zf,
                        const float* __restrict__ gm, uint32_t* __restrict__ keys,
                        u64* __restrict__ binmass, uint32_t* __restrict__ bincnt,
                        float* __restrict__ out) {
  int blk = blockIdx.x, t = threadIdx.x;
  int b = blk / NCB, c = blk % NCB;
  __shared__ float gsh[NDEPTH];
  __shared__ float zsh, msh;
  __shared__ u64 bm[NBINS];
  __shared__ uint32_t bc[NBINS];
  if (t < NDEPTH) gsh[t] = gm[b * NDEPTH + t];
  if (t == 16) zsh = zf[b];
  if (t == 17) msh = mx[b];
  for (int i = t; i < NBINS; i += 256) { bm[i] = 0ull; bc[i] = 0u; }
  __syncthreads();
  size_t base = (size_t)b * NV + (size_t)c * 1024;
  #pragma unroll
  for (int e = 0; e < 4; ++e) {
    size_t i = base + e * 256 + t;
    float p = expf(logits[i] - msh) / zsh;
    uint16_t mk = mask[i];
    #pragma unroll
    for (int d = 0; d < NDEPTH; ++d) {
      float g = (float)((mk >> d) & 1);
      p = p * ((1.0f + g) - gsh[d]);
    }
    uint32_t key = ~__float_as_uint(p);
    keys[i] = key;
    out[i] = 1e-5f;                      // background scores (fill_k folded in)
    uint32_t bin = key >> 23;
    atomicAdd(&bm[bin], (u64)((double)p * MSCALE));
    atomicAdd(&bc[bin], 1u);
  }
  __syncthreads();
  for (int k = t; k < NBINS; k += 256) {
    if (bc[k]) atomicAdd(&bincnt[b * NBINS + k], bc[k]);
    if (bm[k]) atomicAdd(&binmass[b * NBINS + k], bm[k]);
  }
}

// head threshold: single-wave register scan of 512 bins, adaptive margin
__global__ void binsel_k(const u64* __restrict__ binmass, const uint32_t* __restrict__ bincnt,
                         uint32_t* __restrict__ Kthr, uint32_t* __restrict__ Hlen) {
  int b = blockIdx.x, l = threadIdx.x;   // block = 64; lane owns bins [8l, 8l+8)
  u64 m[8]; uint32_t c[8];
  #pragma unroll
  for (int r = 0; r < 8; ++r) {
    m[r] = binmass[b * NBINS + l * 8 + r];
    c[r] = bincnt[b * NBINS + l * 8 + r];
  }
  #pragma unroll
  for (int r = 1; r < 8; ++r) { m[r] += m[r - 1]; c[r] += c[r - 1]; }
  u64 lm = m[7]; uint32_t lc = c[7];
  u64 im = lm; uint32_t ic = lc;
  for (int o = 1; o < 64; o <<= 1) {
    u64 nm = __shfl_up(im, o);
    uint32_t nc = __shfl_up(ic, o);
    if (l >= o) { im += nm; ic += nc; }
  }
  u64 baseM = im - lm;
  uint32_t baseC = ic - lc;
  __shared__ uint32_t ccL[NBINS];
  #pragma unroll
  for (int r = 0; r < 8; ++r) ccL[l * 8 + r] = baseC + c[r];
  const u64 thr = (u64)((double)0.9f * MSCALE);
  int localFirst = 8; u64 cmAt = 0ull;
  #pragma unroll
  for (int r = 0; r < 8; ++r) {
    if (localFirst == 8 && baseM + m[r] >= thr) { localFirst = r; cmAt = baseM + m[r]; }
  }
  u64 bal = __ballot(localFirst < 8);
  int selB = NBINS - 2; u64 cmSel = 0ull;
  if (bal) {
    int fl = __ffsll((unsigned long long)bal) - 1;
    int sl = __shfl(localFirst, fl);
    cmSel = __shfl(cmAt, fl);
    selB = fl * 8 + sl;
  }
  __syncthreads();
  if (l == 0) {
    int margin = (cmSel >= thr && (cmSel - thr) > (1ull << 22)) ? 0 : 1;
    int Bs = selB + margin;
    if (Bs > NBINS - 1) Bs = NBINS - 1;
    while (Bs > 0 && ccL[Bs] > CAP) --Bs;
    Kthr[b] = (uint32_t)((((u64)(Bs + 1)) << 23) - 1ull);
    Hlen[b] = ccL[Bs];
  }
}

// ---- wave-shfl scan over NE=256*NCH counters (dig-major, chunk-minor) -----
template<int NCH, int NL>
__launch_bounds__(1024)
__global__ void rscan_t(uint32_t* __restrict__ cnt) {
  const int NE = 256 * NCH;
  int b = blockIdx.x, t = threadIdx.x, l = t & 63, wv = t >> 6;
  uint32_t* cc = cnt + (size_t)b * NE;
  uint32_t loc[NL];
  uint32_t s = 0;
  int base = t * NL;
  #pragma unroll
  for (int j = 0; j < NL; ++j) {
    loc[j] = (base + j < NE) ? cc[base + j] : 0u;
    s += loc[j];
  }
  uint32_t incl = s;
  for (int o = 1; o < 64; o <<= 1) {
    uint32_t n = __shfl_up(incl, o);
    if (l >= o) incl += n;
  }
  __shared__ uint32_t wtot[16], wbase[16];
  if (l == 63) wtot[wv] = incl;
  __syncthreads();
  if (t < 16) {
    uint32_t v = wtot[t], i2 = v;
    for (int o = 1; o < 16; o <<= 1) {
      uint32_t n = __shfl_up(i2, o);
      if (t >= o) i2 += n;
    }
    wbase[t] = i2 - v;
  }
  __syncthreads();
  uint32_t run = wbase[wv] + (incl - s);
  #pragma unroll
  for (int j = 0; j < NL; ++j) {
    if (base + j < NE) { uint32_t o = loc[j]; cc[base + j] = run; run += o; }
  }
}

// ---- radix pass 1: predicated on full vocab (compaction fused) ------------
__global__ void rhist1_k(const uint32_t* __restrict__ keys, const uint32_t* __restrict__ Kthr,
                         uint32_t* __restrict__ cnt) {
  int blk = blockIdx.x, t = threadIdx.x;
  int b = blk / NCB, c = blk % NCB;
  uint32_t KT = Kthr[b];
  __shared__ uint32_t lh[256];
  lh[t] = 0;
  __syncthreads();
  size_t base = (size_t)b * NV + (size_t)c * 1024;
  #pragma unroll
  for (int e = 0; e < 4; ++e) {
    uint32_t k = keys[base + 256 * e + t];
    if (k <= KT) atomicAdd(&lh[k & 255u], 1u);
  }
  __syncthreads();
  cnt[((size_t)b * 256 + t) * NCB + c] = lh[t];
}

__launch_bounds__(256)
__global__ void rscatter1_k(const uint32_t* __restrict__ keys, const uint32_t* __restrict__ Kthr,
                            const uint32_t* __restrict__ cnt, uint2* __restrict__ dst0) {
  int blk = blockIdx.x, t = threadIdx.x;
  int b = blk / NCB, c = blk % NCB;
  uint32_t KT = Kthr[b];
  uint2* d = dst0 + (size_t)b * CAP;
  int w = t >> 6, lane = t & 63;
  __shared__ uint32_t runb[256];
  __shared__ uint32_t wvc[4][256];
  runb[t] = cnt[((size_t)b * 256 + t) * NCB + c];
  size_t base = (size_t)b * NV + (size_t)c * 1024;
  uint32_t el[4];
  #pragma unroll
  for (int e = 0; e < 4; ++e) el[e] = keys[base + 256 * e + t];
  u64 lowmask = (1ull << lane) - 1ull;
  #pragma unroll
  for (int e = 0; e < 4; ++e) {
    wvc[0][t] = 0; wvc[1][t] = 0; wvc[2][t] = 0; wvc[3][t] = 0;
    __syncthreads();
    bool active = el[e] <= KT;
    uint32_t dig = active ? (el[e] & 255u) : 0u;
    u64 act = __ballot(active);
    u64 m = ~0ull;
    #pragma unroll
    for (int bit = 0; bit < 8; ++bit) {
      u64 bb = __ballot((dig >> bit) & 1u);
      m &= ((dig >> bit) & 1u) ? bb : ~bb;
    }
    m &= act;
    uint32_t rank = (uint32_t)__popcll(m & lowmask);
    if (active && rank == 0) wvc[w][dig] = (uint32_t)__popcll(m);
    __syncthreads();
    if (active) {
      uint32_t off = runb[dig] + rank;
      for (int w2 = 0; w2 < w; ++w2) off += wvc[w2][dig];
      d[off] = make_uint2(el[e], (uint32_t)(c * 1024 + 256 * e + t));
    }
    __syncthreads();
    runb[t] += wvc[0][t] + wvc[1][t] + wvc[2][t] + wvc[3][t];
    __syncthreads();
  }
}

// ---- radix passes 2-4 on the head (early-exit) ----------------------------
__global__ void rhist_k(const uint2* __restrict__ src, const uint32_t* __restrict__ Hlen,
                        uint32_t* __restrict__ cnt, int shift) {
  int blk = blockIdx.x, t = threadIdx.x;
  int b = blk / NBLKH, c = blk % NBLKH;
  uint32_t H = Hlen[b];
  if ((uint32_t)(c * 1024) >= H) { cnt[((size_t)b * 256 + t) * NBLKH + c] = 0u; return; }
  const uint2* s = src + (size_t)b * CAP + (size_t)c * 1024;
  __shared__ uint32_t lh[256];
  lh[t] = 0;
  __syncthreads();
  #pragma unroll
  for (int e = 0; e < 4; ++e) {
    uint32_t idx = (uint32_t)(c * 1024 + 256 * e + t);
    if (idx < H) atomicAdd(&lh[(s[t + 256 * e].x >> shift) & 255u], 1u);
  }
  __syncthreads();
  cnt[((size_t)b * 256 + t) * NBLKH + c] = lh[t];
}

__launch_bounds__(256)
__global__ void rscatter_k(const uint2* __restrict__ src, uint2* __restrict__ dst,
                           const uint32_t* __restrict__ Hlen,
                           const uint32_t* __restrict__ cnt, int shift) {
  int blk = blockIdx.x, t = threadIdx.x;
  int b = blk / NBLKH, c = blk % NBLKH;
  uint32_t H = Hlen[b];
  if ((uint32_t)(c * 1024) >= H) return;
  const uint2* s = src + (size_t)b * CAP + (size_t)c * 1024;
  uint2* d = dst + (size_t)b * CAP;
  int w = t >> 6, lane = t & 63;
  __shared__ uint32_t runb[256];
  __shared__ uint32_t wvc[4][256];
  runb[t] = cnt[((size_t)b * 256 + t) * NBLKH + c];
  uint2 el[4];
  #pragma unroll
  for (int e = 0; e < 4; ++e) el[e] = s[t + 256 * e];
  u64 lowmask = (1ull << lane) - 1ull;
  #pragma unroll
  for (int e = 0; e < 4; ++e) {
    wvc[0][t] = 0; wvc[1][t] = 0; wvc[2][t] = 0; wvc[3][t] = 0;
    __syncthreads();
    bool active = (uint32_t)(c * 1024 + 256 * e + t) < H;
    uint32_t dig = active ? ((el[e].x >> shift) & 255u) : 0u;
    u64 act = __ballot(active);
    u64 m = ~0ull;
    #pragma unroll
    for (int bit = 0; bit < 8; ++bit) {
      u64 bb = __ballot((dig >> bit) & 1u);
      m &= ((dig >> bit) & 1u) ? bb : ~bb;
    }
    m &= act;
    uint32_t rank = (uint32_t)__popcll(m & lowmask);
    if (active && rank == 0) wvc[w][dig] = (uint32_t)__popcll(m);
    __syncthreads();
    if (active) {
      uint32_t off = runb[dig] + rank;
      for (int w2 = 0; w2 < w; ++w2) off += wvc[w2][dig];
      d[off] = el[e];
    }
    __syncthreads();
    runb[t] += wvc[0][t] + wvc[1][t] + wvc[2][t] + wvc[3][t];
    __syncthreads();
  }
}

// ---------------------------------------------------------------------------
__global__ void chunks_k(const uint2* __restrict__ sp, const uint32_t* __restrict__ Hlen,
                         double* __restrict__ cs) {
  int blk = blockIdx.x, t = threadIdx.x;
  int b = blk / NBLKH, c = blk % NBLKH;
  uint32_t H = Hlen[b];
  if ((uint32_t)(c * 1024) >= H) { if (t == 0) cs[b * NBLKH + c] = 0.0; return; }
  const uint2* p = sp + (size_t)b * CAP + (size_t)c * 1024;
  double s = 0.0;
  for (int k = t; k < 1024; k += 256) {
    uint32_t idx = (uint32_t)(c * 1024 + k);
    if (idx < H) s += (double)__uint_as_float(~p[k].x);
  }
  __shared__ double red[256];
  red[t] = s; __syncthreads();
  for (int st = 128; st > 0; st >>= 1) {
    if (t < st) red[t] += red[t + st];
    __syncthreads();
  }
  if (t == 0) cs[b * NBLKH + c] = red[0];
}

// fused cutoff (wave-shfl f64 scans) + gumbel argmax
__launch_bounds__(1024)
__global__ void cutargmax_k(const uint2* __restrict__ sp, const double* __restrict__ cs,
                            const uint32_t* __restrict__ Hlen,
                            const uint32_t* __restrict__ sk, u64* __restrict__ best) {
  int b = blockIdx.x, t = threadIdx.x, l = t & 63, wv = t >> 6;
  const double TOPP = (double)0.9f;
  uint32_t H = Hlen[b];
  __shared__ double sh_base;
  __shared__ int sh_ch;
  __shared__ uint32_t sh_cut;
  __shared__ double wsum[16];
  __shared__ u64 wmx[16];
  __shared__ int kSel;
  if (t == 0) { sh_ch = -1; sh_base = 0.0; sh_cut = H - 1; kSel = 1023; }
  __syncthreads();
  if (wv == 0) {
    double v0 = (l < NBLKH) ? cs[b * NBLKH + l] : 0.0;
    double v1 = (l + 64 < NBLKH) ? cs[b * NBLKH + l + 64] : 0.0;
    double i0 = v0;
    for (int o = 1; o < 64; o <<= 1) { double n = __shfl_up(i0, o); if (l >= o) i0 += n; }
    double T0 = __shfl(i0, 63);
    double i1 = v1;
    for (int o = 1; o < 64; o <<= 1) { double n = __shfl_up(i1, o); if (l >= o) i1 += n; }
    i1 += T0;
    bool h0 = (l < NBLKH) && (i0 >= TOPP);
    bool h1 = (l + 64 < NBLKH) && (i1 >= TOPP);
    u64 b0m = __ballot(h0);
    u64 b1m = __ballot(h1);
    int ch = -1; double bse = 0.0;
    if (b0m) {
      int fl = __ffsll((unsigned long long)b0m) - 1;
      ch = fl; bse = __shfl(i0, fl) - __shfl(v0, fl);
    } else if (b1m) {
      int fl = __ffsll((unsigned long long)b1m) - 1;
      ch = 64 + fl; bse = __shfl(i1, fl) - __shfl(v1, fl);
    }
    if (l == 0) { sh_ch = ch; sh_base = bse; }
  }
  __syncthreads();
  int CH = sh_ch;
  if (CH >= 0) {
    double base = sh_base;
    uint32_t idx = (uint32_t)(CH * 1024 + t);
    double pv = (idx < H) ? (double)__uint_as_float(~sp[(size_t)b * CAP + idx].x) : 0.0;
    double iv = pv;
    for (int o = 1; o < 64; o <<= 1) { double n = __shfl_up(iv, o); if (l >= o) iv += n; }
    if (l == 63) wsum[wv] = iv;
    __syncthreads();
    if (t < 16) {
      double v = wsum[t], i2 = v;
      for (int o = 1; o < 16; o <<= 1) { double n = __shfl_up(i2, o); if (t >= o) i2 += n; }
      wsum[t] = i2 - v;
    }
    __syncthreads();
    double full = base + wsum[wv] + iv;
    double prev = full - pv;
    if (full >= TOPP && prev < TOPP) atomicMin(&kSel, (int)t);
    __syncthreads();
    if (t == 0) sh_cut = (uint32_t)(CH * 1024 + (kSel < 1024 ? kSel : 1023));
  }
  __syncthreads();
  uint32_t c = sh_cut;
  uint32_t k0 = sk[2 * b], k1 = sk[2 * b + 1];
  u64 loc = 0ull;
  for (uint32_t j = (uint32_t)t; j <= c; j += 1024) {
    uint32_t bits = random_bits32(k0, k1, j);
    uint32_t m = bits >> 9;
    float u = (m == 0u) ? 1.17549435e-38f : (float)m * 1.1920928955078125e-7f;
    float gum = -logf(-logf(u));
    float scv = logf(__uint_as_float(~sp[(size_t)b * CAP + j].x)) + gum;
    uint32_t su = __float_as_uint(scv);
    uint32_t ord = (su & 0x80000000u) ? ~su : (su | 0x80000000u);
    u64 pk = ((u64)ord << 32) | (u64)(0xFFFFFFFFu - j);
    loc = (pk > loc) ? pk : loc;
  }
  for (int o = 32; o > 0; o >>= 1) {
    u64 oth = __shfl_xor(loc, o);
    loc = (oth > loc) ? oth : loc;
  }
  if (l == 0) wmx[wv] = loc;
  __syncthreads();
  if (t == 0) {
    u64 m = wmx[0];
    for (int k = 1; k < 16; ++k) m = (wmx[k] > m) ? wmx[k] : m;
    best[b] = m;
  }
}

__global__ void win_k(const u64* __restrict__ best, const uint2* __restrict__ sp,
                      float* __restrict__ out) {
  int b = threadIdx.x;
  if (b >= NB) return;
  u64 pk = best[b];
  uint32_t j = 0xFFFFFFFFu - (uint32_t)(pk & 0xFFFFFFFFull);
  uint32_t tok = sp[(size_t)b * CAP + j].y;
  out[(size_t)b * NV + tok] = 100000.0f;
}

// ---------------------------------------------------------------------------
extern "C" void kernel_launch(void* const* d_in, const int* in_sizes, int n_in,
                              void* d_out, int out_size, void* d_ws, size_t ws_size,
                              hipStream_t stream) {
  const int* ids = (const int*)d_in[0];
  const float* logits = (const float*)d_in[1];
  float* out = (float*)d_out;
  int T = in_sizes[0] / NB;

  char* w = (char*)d_ws;
  uint2*    headA = (uint2*)(w + 0);                  // 24,641,536
  uint2*    headB = (uint2*)(w + 24641536);           // 24,641,536
  uint32_t* keys  = (uint32_t*)(w + 24641536);        // aliases headB (dead before pass 2)
  uint32_t* cnt   = (uint32_t*)(w + 49283072);        //  4,096,000
  uint16_t* mask  = (uint16_t*)(w + 53379072);        //  8,192,000
  char* S = w + 61571072;
  float*    pmax    = (float*)(S + 0);                // 64,000
  double*   csum    = (double*)(S + 64000);           // 24,064
  float*    mx      = (float*)(S + 88064);            // 128
  float*    zf      = (float*)(S + 88192);            // 128
  float*    gm      = (float*)(S + 88320);            // 2,048
  uint32_t* Kthr    = (uint32_t*)(S + 90368);         // 128
  uint32_t* Hlen    = (uint32_t*)(S + 90496);         // 128
  u64*      Zint    = (u64*)(S + 90624);              // 256
  float*    wloTab  = (float*)(S + 90880);            // 32,768
  u64*      best    = (u64*)(S + 123648);             // 256
  uint32_t* kd      = (uint32_t*)(S + 123904);        // 4,096
  uint32_t* sk      = (uint32_t*)(S + 128000);        // 256
  char* ZR = S + 128256;                              // zeroed by gmaskmax
  u64*      Hlo     = (u64*)(ZR + 0);                 // 65,536
  u64*      Thist   = (u64*)(ZR + 65536);             // 65,536
  u64*      binmass = (u64*)(ZR + 131072);            // 131,072
  uint32_t* bincnt  = (uint32_t*)(ZR + 262144);       // 65,536

  const int BVBLK = NB * NTB;   // 16,000
  const int CBLK  = NB * NCB;   //  4,000

  keys_k<<<1, 64, 0, stream>>>(ids, T, kd, sk);
  gmaskmax_k<<<BVBLK, 256, 0, stream>>>(kd, logits, mask, pmax, (uint32_t*)ZR);
  maxr2_k<<<1, 1024, 0, stream>>>(pmax, mx);
  lohist_k<<<CBLK, 256, 0, stream>>>(logits, mask, mx, Hlo);
  faclo_k<<<NB, 64, 0, stream>>>(Hlo, Zint, zf, gm, wloTab);
  hihist_k<<<CBLK, 256, 0, stream>>>(logits, mask, mx, wloTab, Thist);
  fachi_k<<<NB, 64, 0, stream>>>(Thist, Zint, gm);
  final_k<<<CBLK, 256, 0, stream>>>(logits, mask, mx, zf, gm, keys, binmass, bincnt, out);
  binsel_k<<<NB, 64, 0, stream>>>(binmass, bincnt, Kthr, Hlen);

  // pass 1: predicated full-vocab -> compacted + LSB-sorted head in headA
  rhist1_k<<<CBLK, 256, 0, stream>>>(keys, Kthr, cnt);
  rscan_t<NCB, 32><<<NB, 1024, 0, stream>>>(cnt);
  rscatter1_k<<<CBLK, 256, 0, stream>>>(keys, Kthr, cnt, headA);

  // passes 2-4 on the head: A->B->A->B (sorted result in headB)
  const uint2* srcs[3] = { headA, headB, headA };
  uint2*       dsts[3] = { headB, headA, headB };
  for (int pass = 0; pass < 3; ++pass) {
    int shift = (pass + 1) * 8;
    rhist_k<<<NB * NBLKH, 256, 0, stream>>>(srcs[pass], Hlen, cnt, shift);
    rscan_t<NBLKH, 24><<<NB, 1024, 0, stream>>>(cnt);
    rscatter_k<<<NB * NBLKH, 256, 0, stream>>>(srcs[pass], dsts[pass], Hlen, cnt, shift);
  }

  chunks_k<<<NB * NBLKH, 256, 0, stream>>>(headB, Hlen, csum);
  cutargmax_k<<<NB, 1024, 0, stream>>>(headB, csum, Hlen, sk, best);
  win_k<<<1, 32, 0, stream>>>(best, headB, out);
}